// Round 1
// baseline (8749.011 us; speedup 1.0000x reference)
//
#include <hip/hip_runtime.h>
#include <hip/hip_bf16.h>
#include <cstddef>

#define BB 16
#define TT 32
#define VV 1003
#define EE 100
#define HH 2048
#define G4 8192  // 4*H

// ---------------- embedding gather ----------------
__global__ __launch_bounds__(256) void embed_kernel(
    const int* __restrict__ tokens, const float* __restrict__ emb,
    float* __restrict__ x) {
  int i = blockIdx.x * 256 + threadIdx.x;
  if (i < BB * TT * EE) {
    int r = i / EE, e = i - r * EE;
    x[i] = emb[(size_t)tokens[r] * EE + e];
  }
}

// ---------------- xz = X @ W + b, written as xz[t][b][col] ----------------
// X: [512][K] row-major, row r = b*32 + t.  W: [K][8192].
// Tile 64x128, 256 threads, 4x8 micro-tile.
__global__ __launch_bounds__(256) void gemm_xz(
    const float* __restrict__ X, int K,
    const float* __restrict__ W,
    const float* __restrict__ bias,
    float* __restrict__ xz) {
  __shared__ float As[16][68];   // A transposed, padded for 16B-aligned float4
  __shared__ float Bs[16][128];
  int tid = threadIdx.x;
  int tx = tid & 15, ty = tid >> 4;
  int row0 = blockIdx.y * 64, col0 = blockIdx.x * 128;
  float acc[4][8];
#pragma unroll
  for (int i = 0; i < 4; i++)
#pragma unroll
    for (int j = 0; j < 8; j++) acc[i][j] = 0.f;

  for (int k0 = 0; k0 < K; k0 += 16) {
    // load A tile 64x16 (transposed into As[kk][m])
    for (int i = tid; i < 64 * 16; i += 256) {
      int m = i >> 4, kk = i & 15;
      int gk = k0 + kk;
      As[kk][m] = (gk < K) ? X[(size_t)(row0 + m) * K + gk] : 0.f;
    }
    // load B tile 16x128
    for (int i = tid; i < 16 * 128; i += 256) {
      int kk = i >> 7, n = i & 127;
      int gk = k0 + kk;
      Bs[kk][n] = (gk < K) ? W[(size_t)gk * G4 + col0 + n] : 0.f;
    }
    __syncthreads();
#pragma unroll
    for (int kk = 0; kk < 16; ++kk) {
      float4 av = *(const float4*)&As[kk][ty * 4];
      float4 bv0 = *(const float4*)&Bs[kk][tx * 8];
      float4 bv1 = *(const float4*)&Bs[kk][tx * 8 + 4];
      float a[4] = {av.x, av.y, av.z, av.w};
      float b[8] = {bv0.x, bv0.y, bv0.z, bv0.w, bv1.x, bv1.y, bv1.z, bv1.w};
#pragma unroll
      for (int i = 0; i < 4; i++)
#pragma unroll
        for (int j = 0; j < 8; j++) acc[i][j] = fmaf(a[i], b[j], acc[i][j]);
    }
    __syncthreads();
  }
#pragma unroll
  for (int i = 0; i < 4; i++) {
    int r = row0 + ty * 4 + i;
    int b = r >> 5, t = r & 31;
    float* dst = xz + ((size_t)t * BB + b) * G4;
#pragma unroll
    for (int j = 0; j < 8; j++) {
      int cg = col0 + tx * 8 + j;
      dst[cg] = acc[i][j] + bias[cg];
    }
  }
}

// ---------------- one LSTM step, fused: z = xz_t + h@U; gates; masked c/h ----
// grid = 128 blocks (16 hidden units each), 512 threads (8 K-groups x 64 lanes)
// hT layout: [2048][16] (k-major).  c: [16][2048].  allh: [b][t][h].
__global__ __launch_bounds__(512) void lstm_step(
    const float* __restrict__ U,      // [2048][8192]
    const float* __restrict__ xzt,    // [16][8192] for this t
    const float* __restrict__ hT_in,  // [2048][16]
    float* __restrict__ hT_out,       // [2048][16]
    float* __restrict__ c,            // [16][2048]
    float* __restrict__ allh,         // [16][32][2048]
    const int* __restrict__ tokens,   // [16][32]
    int t) {
  __shared__ float red[8][16][64];    // 32 KB
  __shared__ float zbuf[16][64];      // 4 KB
  int tid = threadIdx.x;
  int kg = tid >> 6;                  // 0..7, each owns 256 k
  int lane = tid & 63;
  int g = lane >> 4, ci = lane & 15;
  int hu0 = blockIdx.x * 16;
  int col = g * HH + hu0 + ci;

  float acc[16];
#pragma unroll
  for (int i = 0; i < 16; i++) acc[i] = 0.f;

  const float* Up = U + (size_t)(kg * 256) * G4 + col;
  const float4* h4 = (const float4*)(hT_in + (size_t)kg * 256 * BB);
#pragma unroll 4
  for (int k = 0; k < 256; k++) {
    float u = Up[(size_t)k * G4];
    float4 h0 = h4[k * 4 + 0];
    float4 h1 = h4[k * 4 + 1];
    float4 h2 = h4[k * 4 + 2];
    float4 h3 = h4[k * 4 + 3];
    acc[0]  = fmaf(h0.x, u, acc[0]);  acc[1]  = fmaf(h0.y, u, acc[1]);
    acc[2]  = fmaf(h0.z, u, acc[2]);  acc[3]  = fmaf(h0.w, u, acc[3]);
    acc[4]  = fmaf(h1.x, u, acc[4]);  acc[5]  = fmaf(h1.y, u, acc[5]);
    acc[6]  = fmaf(h1.z, u, acc[6]);  acc[7]  = fmaf(h1.w, u, acc[7]);
    acc[8]  = fmaf(h2.x, u, acc[8]);  acc[9]  = fmaf(h2.y, u, acc[9]);
    acc[10] = fmaf(h2.z, u, acc[10]); acc[11] = fmaf(h2.w, u, acc[11]);
    acc[12] = fmaf(h3.x, u, acc[12]); acc[13] = fmaf(h3.w == h3.w ? h3.y : h3.y, u, acc[13]);
    acc[14] = fmaf(h3.z, u, acc[14]); acc[15] = fmaf(h3.w, u, acc[15]);
  }
#pragma unroll
  for (int b = 0; b < 16; b++) red[kg][b][lane] = acc[b];
  __syncthreads();

  // reduce 8 partials; add xz
  for (int i = tid; i < 1024; i += 512) {
    int b = i >> 6, l = i & 63;
    float s = 0.f;
#pragma unroll
    for (int q = 0; q < 8; q++) s += red[q][b][l];
    int gg = l >> 4, cc = l & 15;
    zbuf[b][l] = s + xzt[(size_t)b * G4 + gg * HH + hu0 + cc];
  }
  __syncthreads();

  // cell update: 256 threads, one (b, hu) each
  if (tid < 256) {
    int b = tid >> 4, cc = tid & 15;
    int hu = hu0 + cc;
    float zi = zbuf[b][0 * 16 + cc];
    float zf = zbuf[b][1 * 16 + cc];
    float zg = zbuf[b][2 * 16 + cc];
    float zo = zbuf[b][3 * 16 + cc];
    float ig = 1.f / (1.f + expf(-zi));
    float fg = 1.f / (1.f + expf(-zf));
    float gg2 = tanhf(zg);
    float og = 1.f / (1.f + expf(-zo));
    float c_old = c[(size_t)b * HH + hu];
    float c_new = fg * c_old + ig * gg2;
    float h_new = og * tanhf(c_new);
    bool m = tokens[b * TT + t] != 0;
    if (!m) {
      c_new = c_old;
      h_new = hT_in[(size_t)hu * BB + b];
    }
    c[(size_t)b * HH + hu] = c_new;
    hT_out[(size_t)hu * BB + b] = h_new;
    allh[((size_t)b * TT + t) * HH + hu] = h_new;
  }
}

// ---------------- small-M GEMM for the head: out = XT^T @ W + bias ----------
// XT: [K][16] k-major. out element (b, col) written at col*sc + b*sb.
__global__ __launch_bounds__(256) void smallgemm(
    const float* __restrict__ XT, const float* __restrict__ W,
    const float* __restrict__ bias, float* __restrict__ out,
    int K, int N, int sc, int sb) {
  __shared__ float red[8][16][32];
  int tid = threadIdx.x;
  int kg = tid >> 5;       // 8 groups
  int cl = tid & 31;
  int col = blockIdx.x * 32 + cl;
  int kpg = K >> 3;
  float acc[16];
#pragma unroll
  for (int i = 0; i < 16; i++) acc[i] = 0.f;
  if (col < N) {
    const float* Wp = W + (size_t)(kg * kpg) * N + col;
    const float4* x4 = (const float4*)(XT + (size_t)kg * kpg * BB);
    for (int k = 0; k < kpg; k++) {
      float w = Wp[(size_t)k * N];
      float4 a = x4[k * 4 + 0];
      float4 b = x4[k * 4 + 1];
      float4 cc = x4[k * 4 + 2];
      float4 d = x4[k * 4 + 3];
      acc[0]  = fmaf(a.x, w, acc[0]);  acc[1]  = fmaf(a.y, w, acc[1]);
      acc[2]  = fmaf(a.z, w, acc[2]);  acc[3]  = fmaf(a.w, w, acc[3]);
      acc[4]  = fmaf(b.x, w, acc[4]);  acc[5]  = fmaf(b.y, w, acc[5]);
      acc[6]  = fmaf(b.z, w, acc[6]);  acc[7]  = fmaf(b.w, w, acc[7]);
      acc[8]  = fmaf(cc.x, w, acc[8]); acc[9]  = fmaf(cc.y, w, acc[9]);
      acc[10] = fmaf(cc.z, w, acc[10]);acc[11] = fmaf(cc.w, w, acc[11]);
      acc[12] = fmaf(d.x, w, acc[12]); acc[13] = fmaf(d.y, w, acc[13]);
      acc[14] = fmaf(d.z, w, acc[14]); acc[15] = fmaf(d.w, w, acc[15]);
    }
  }
#pragma unroll
  for (int b = 0; b < 16; b++) red[kg][b][cl] = acc[b];
  __syncthreads();
  for (int i = tid; i < 512; i += 256) {
    int b = i >> 5, l = i & 31;
    int cg = blockIdx.x * 32 + l;
    if (cg < N) {
      float s = 0.f;
#pragma unroll
      for (int q = 0; q < 8; q++) s += red[q][b][l];
      out[(size_t)cg * sc + (size_t)b * sb] = s + bias[cg];
    }
  }
}

// ---------------- softmax over rows of [16][1003] ----------------
__global__ __launch_bounds__(256) void softmax_rows(
    const float* __restrict__ logits, float* __restrict__ out, int N) {
  __shared__ float buf[1024];
  __shared__ float wred[4];
  __shared__ float rmax, rsum;
  int b = blockIdx.x, tid = threadIdx.x;
  float m = -1e30f;
  for (int v = tid; v < N; v += 256) {
    float x = logits[(size_t)b * N + v];
    buf[v] = x;
    m = fmaxf(m, x);
  }
  for (int o = 32; o > 0; o >>= 1) m = fmaxf(m, __shfl_down(m, o, 64));
  if ((tid & 63) == 0) wred[tid >> 6] = m;
  __syncthreads();
  if (tid == 0) rmax = fmaxf(fmaxf(wred[0], wred[1]), fmaxf(wred[2], wred[3]));
  __syncthreads();
  float s = 0.f;
  for (int v = tid; v < N; v += 256) {
    float e = expf(buf[v] - rmax);
    buf[v] = e;
    s += e;
  }
  for (int o = 32; o > 0; o >>= 1) s += __shfl_down(s, o, 64);
  if ((tid & 63) == 0) wred[tid >> 6] = s;
  __syncthreads();
  if (tid == 0) rsum = wred[0] + wred[1] + wred[2] + wred[3];
  __syncthreads();
  float inv = 1.f / rsum;
  for (int v = tid; v < N; v += 256) out[(size_t)b * N + v] = buf[v] * inv;
}

extern "C" void kernel_launch(void* const* d_in, const int* in_sizes, int n_in,
                              void* d_out, int out_size, void* d_ws, size_t ws_size,
                              hipStream_t stream) {
  const int*   tokens = (const int*)d_in[0];
  const float* emb  = (const float*)d_in[1];
  const float* W1   = (const float*)d_in[2];
  const float* U1   = (const float*)d_in[3];
  const float* b1   = (const float*)d_in[4];
  const float* W2   = (const float*)d_in[5];
  const float* U2   = (const float*)d_in[6];
  const float* b2   = (const float*)d_in[7];
  const float* W3   = (const float*)d_in[8];
  const float* U3   = (const float*)d_in[9];
  const float* b3   = (const float*)d_in[10];
  const float* Wd1  = (const float*)d_in[11];
  const float* bd1  = (const float*)d_in[12];
  const float* Wd2  = (const float*)d_in[13];
  const float* bd2  = (const float*)d_in[14];
  float* out = (float*)d_out;

  float* ws = (float*)d_ws;
  size_t off = 0;
  float* x_emb = ws + off; off += 51264;                 // 512*100 padded
  float* xz    = ws + off; off += (size_t)TT * BB * G4;  // 4,194,304
  float* allh1 = ws + off; off += (size_t)BB * TT * HH;
  float* allh2 = ws + off; off += (size_t)BB * TT * HH;
  float* allh3 = ws + off; off += (size_t)BB * TT * HH;
  float* hT0   = ws + off; off += HH * BB;
  float* cbuf  = ws + off; off += HH * BB;               // contiguous with hT0
  float* hT1   = ws + off; off += HH * BB;
  float* yT    = ws + off; off += HH * BB;
  float* logits = ws + off; off += 16384;

  float* hping[2] = {hT0, hT1};

  const float* Ws[3] = {W1, W2, W3};
  const float* Us[3] = {U1, U2, U3};
  const float* bs[3] = {b1, b2, b3};
  float* allhs[3] = {allh1, allh2, allh3};
  const float* Xs[3] = {x_emb, allh1, allh2};
  int Ks[3] = {EE, HH, HH};

  embed_kernel<<<dim3((BB * TT * EE + 255) / 256), 256, 0, stream>>>(tokens, emb, x_emb);

  for (int layer = 0; layer < 3; layer++) {
    gemm_xz<<<dim3(G4 / 128, (BB * TT) / 64), 256, 0, stream>>>(
        Xs[layer], Ks[layer], Ws[layer], bs[layer], xz);
    (void)hipMemsetAsync(hT0, 0, 2 * HH * BB * sizeof(float), stream);  // hT0 + cbuf
    for (int t = 0; t < TT; t++) {
      lstm_step<<<dim3(HH / 16), 512, 0, stream>>>(
          Us[layer], xz + (size_t)t * BB * G4, hping[t & 1], hping[(t + 1) & 1],
          cbuf, allhs[layer], tokens, t);
    }
  }

  // final h is in hT0 (T even). Head:
  smallgemm<<<dim3(HH / 32), 256, 0, stream>>>(hT0, Wd1, bd1, yT, HH, HH, 16, 1);
  smallgemm<<<dim3((VV + 31) / 32), 256, 0, stream>>>(yT, Wd2, bd2, logits, HH, VV, 1, VV);
  softmax_rows<<<dim3(BB), 256, 0, stream>>>(logits, out, VV);
}

// Round 2
// 4010.366 us; speedup vs baseline: 2.1816x; 2.1816x over previous
//
#include <hip/hip_runtime.h>
#include <hip/hip_bf16.h>
#include <cstddef>

#define BB 16
#define TT 32
#define VV 1003
#define EE 100
#define HH 2048
#define G4 8192  // 4*H

// ---------------- embedding gather ----------------
__global__ __launch_bounds__(256) void embed_kernel(
    const int* __restrict__ tokens, const float* __restrict__ emb,
    float* __restrict__ x) {
  int i = blockIdx.x * 256 + threadIdx.x;
  if (i < BB * TT * EE) {
    int r = i / EE, e = i - r * EE;
    x[i] = emb[(size_t)tokens[r] * EE + e];
  }
}

// ---------------- xz = X @ W + b, written as xz[t][b][col] ----------------
// X: [512][K] row-major, row r = b*32 + t.  W: [K][8192].
// Tile 64x128, 256 threads, 4x8 micro-tile, K-tile 32, reg-prefetch pipeline.
__global__ __launch_bounds__(256) void gemm_xz(
    const float* __restrict__ X, int K,
    const float* __restrict__ W,
    const float* __restrict__ bias,
    float* __restrict__ xz) {
  __shared__ float As[64][36];    // row-major A tile, broadcast scalar reads
  __shared__ float Bs[32][132];
  int tid = threadIdx.x;
  int tx = tid & 15, ty = tid >> 4;
  int row0 = blockIdx.y * 64, col0 = blockIdx.x * 128;

  // A loader: row ra, k-offset ka..ka+7 (two float4)
  int ra = tid >> 2, ka = (tid & 3) * 8;
  // B loader: rows kbr+8q, cols cb..cb+3
  int kbr = tid >> 5, cb = (tid & 31) * 4;

  const float* Arow = X + (size_t)(row0 + ra) * K;

  float acc[4][8];
#pragma unroll
  for (int i = 0; i < 4; i++)
#pragma unroll
    for (int j = 0; j < 8; j++) acc[i][j] = 0.f;

  float pa[8];
  float pb[16];
  int ntile = (K + 31) / 32;

  // ---- load tile 0 ----
  {
    int k0 = 0;
    if (ka + 7 < K) {
      float4 v0 = *(const float4*)(Arow + k0 + ka);
      float4 v1 = *(const float4*)(Arow + k0 + ka + 4);
      pa[0] = v0.x; pa[1] = v0.y; pa[2] = v0.z; pa[3] = v0.w;
      pa[4] = v1.x; pa[5] = v1.y; pa[6] = v1.z; pa[7] = v1.w;
    } else {
#pragma unroll
      for (int j = 0; j < 8; j++) pa[j] = (k0 + ka + j < K) ? Arow[k0 + ka + j] : 0.f;
    }
#pragma unroll
    for (int q = 0; q < 4; q++) {
      int gk = k0 + kbr + 8 * q;
      if (gk < K) {
        float4 v = *(const float4*)(W + (size_t)gk * G4 + col0 + cb);
        pb[q * 4 + 0] = v.x; pb[q * 4 + 1] = v.y; pb[q * 4 + 2] = v.z; pb[q * 4 + 3] = v.w;
      } else {
        pb[q * 4 + 0] = 0.f; pb[q * 4 + 1] = 0.f; pb[q * 4 + 2] = 0.f; pb[q * 4 + 3] = 0.f;
      }
    }
    *(float4*)&As[ra][ka] = make_float4(pa[0], pa[1], pa[2], pa[3]);
    *(float4*)&As[ra][ka + 4] = make_float4(pa[4], pa[5], pa[6], pa[7]);
#pragma unroll
    for (int q = 0; q < 4; q++)
      *(float4*)&Bs[kbr + 8 * q][cb] = make_float4(pb[q * 4], pb[q * 4 + 1], pb[q * 4 + 2], pb[q * 4 + 3]);
  }
  __syncthreads();

  for (int tix = 0; tix < ntile; tix++) {
    // prefetch next tile into registers
    if (tix + 1 < ntile) {
      int k0 = (tix + 1) * 32;
      if (k0 + ka + 7 < K) {
        float4 v0 = *(const float4*)(Arow + k0 + ka);
        float4 v1 = *(const float4*)(Arow + k0 + ka + 4);
        pa[0] = v0.x; pa[1] = v0.y; pa[2] = v0.z; pa[3] = v0.w;
        pa[4] = v1.x; pa[5] = v1.y; pa[6] = v1.z; pa[7] = v1.w;
      } else {
#pragma unroll
        for (int j = 0; j < 8; j++) pa[j] = (k0 + ka + j < K) ? Arow[k0 + ka + j] : 0.f;
      }
#pragma unroll
      for (int q = 0; q < 4; q++) {
        int gk = k0 + kbr + 8 * q;
        if (gk < K) {
          float4 v = *(const float4*)(W + (size_t)gk * G4 + col0 + cb);
          pb[q * 4 + 0] = v.x; pb[q * 4 + 1] = v.y; pb[q * 4 + 2] = v.z; pb[q * 4 + 3] = v.w;
        } else {
          pb[q * 4 + 0] = 0.f; pb[q * 4 + 1] = 0.f; pb[q * 4 + 2] = 0.f; pb[q * 4 + 3] = 0.f;
        }
      }
    }
    // compute current tile
#pragma unroll
    for (int kk = 0; kk < 32; kk++) {
      float a0 = As[ty * 4 + 0][kk];
      float a1 = As[ty * 4 + 1][kk];
      float a2 = As[ty * 4 + 2][kk];
      float a3 = As[ty * 4 + 3][kk];
      float4 b0 = *(const float4*)&Bs[kk][tx * 4];
      float4 b1 = *(const float4*)&Bs[kk][64 + tx * 4];
      float bv[8] = {b0.x, b0.y, b0.z, b0.w, b1.x, b1.y, b1.z, b1.w};
      float av[4] = {a0, a1, a2, a3};
#pragma unroll
      for (int i = 0; i < 4; i++)
#pragma unroll
        for (int j = 0; j < 8; j++) acc[i][j] = fmaf(av[i], bv[j], acc[i][j]);
    }
    if (tix + 1 < ntile) {
      __syncthreads();
      *(float4*)&As[ra][ka] = make_float4(pa[0], pa[1], pa[2], pa[3]);
      *(float4*)&As[ra][ka + 4] = make_float4(pa[4], pa[5], pa[6], pa[7]);
#pragma unroll
      for (int q = 0; q < 4; q++)
        *(float4*)&Bs[kbr + 8 * q][cb] = make_float4(pb[q * 4], pb[q * 4 + 1], pb[q * 4 + 2], pb[q * 4 + 3]);
      __syncthreads();
    }
  }

#pragma unroll
  for (int i = 0; i < 4; i++) {
    int r = row0 + ty * 4 + i;
    int b = r >> 5, tt = r & 31;
    float* dst = xz + ((size_t)tt * BB + b) * G4;
#pragma unroll
    for (int j = 0; j < 4; j++) {
      int c0 = col0 + tx * 4 + j;
      int c1 = col0 + 64 + tx * 4 + j;
      dst[c0] = acc[i][j] + bias[c0];
      dst[c1] = acc[i][j + 4] + bias[c1];
    }
  }
}

// ---------------- one LSTM step: partials + closing-block gates ----------
// grid = 256 blocks = 32 colgroups (64 hid units x 4 gates) x 8 k-blocks.
// block = 256 threads = 4 waves; wave owns 64 k; lane owns float4 of cols.
// hT layout: [2048][16] k-major.  c: [16][2048].  allh: [b][t][h].
__global__ __launch_bounds__(256) void lstm_step(
    const float* __restrict__ U,      // [2048][8192]
    const float* __restrict__ xzt,    // [16][8192] for this t
    const float* __restrict__ hT_in,  // [2048][16]
    float* __restrict__ hT_out,       // [2048][16]
    float* __restrict__ c,            // [16][2048]
    float* __restrict__ allh,         // [16][32][2048]
    const int* __restrict__ tokens,   // [16][32]
    int t,
    float* __restrict__ partial,      // [8][16][8192]
    int* __restrict__ ctr) {          // [32][32] step x colgroup
  __shared__ float red[4][16][256];   // 64 KB
  __shared__ float hsh[256 * BB];     // 16 KB staged h chunk
  __shared__ int flag;
  int tid = threadIdx.x;
  int wave = tid >> 6, lane = tid & 63;
  int cg = blockIdx.x & 31, kb = blockIdx.x >> 5;
  int hu0 = cg * 64;
  int g = lane >> 4, hi = lane & 15;
  int colbase = g * HH + hu0 + hi * 4;

  // stage this k-block's h chunk (256 k x 16 b) into LDS
  const float* hsrc = hT_in + (size_t)kb * 256 * BB;
  for (int i = tid; i < 256 * BB; i += 256) hsh[i] = hsrc[i];
  __syncthreads();

  float4 acc[16];
#pragma unroll
  for (int b = 0; b < 16; b++) acc[b] = make_float4(0.f, 0.f, 0.f, 0.f);

  const float* Ub = U + ((size_t)kb * 256 + (size_t)wave * 64) * G4 + colbase;
  const float* hb = hsh + wave * 64 * BB;

#pragma unroll 4
  for (int k = 0; k < 64; k++) {
    float4 u = *(const float4*)(Ub + (size_t)k * G4);
    float4 h0 = *(const float4*)(hb + k * BB + 0);
    float4 h1 = *(const float4*)(hb + k * BB + 4);
    float4 h2 = *(const float4*)(hb + k * BB + 8);
    float4 h3 = *(const float4*)(hb + k * BB + 12);
#define FMA4(A, s) \
    A.x = fmaf(s, u.x, A.x); A.y = fmaf(s, u.y, A.y); \
    A.z = fmaf(s, u.z, A.z); A.w = fmaf(s, u.w, A.w)
    FMA4(acc[0], h0.x);  FMA4(acc[1], h0.y);  FMA4(acc[2], h0.z);  FMA4(acc[3], h0.w);
    FMA4(acc[4], h1.x);  FMA4(acc[5], h1.y);  FMA4(acc[6], h1.z);  FMA4(acc[7], h1.w);
    FMA4(acc[8], h2.x);  FMA4(acc[9], h2.y);  FMA4(acc[10], h2.z); FMA4(acc[11], h2.w);
    FMA4(acc[12], h3.x); FMA4(acc[13], h3.y); FMA4(acc[14], h3.z); FMA4(acc[15], h3.w);
#undef FMA4
  }

#pragma unroll
  for (int b = 0; b < 16; b++)
    *(float4*)&red[wave][b][lane * 4] = acc[b];
  __syncthreads();

  // reduce 4 wave-partials -> block partial, write to global
  for (int i = tid; i < 16 * 256; i += 256) {
    int b = i >> 8, cl = i & 255;
    float s = red[0][b][cl] + red[1][b][cl] + red[2][b][cl] + red[3][b][cl];
    int gg = cl >> 6, rem = cl & 63;
    partial[((size_t)(kb * 16 + b)) * G4 + gg * HH + hu0 + rem] = s;
  }
  __syncthreads();  // all partial stores issued & drained (vmcnt before barrier)

  if (tid == 0) {
    __threadfence();                      // flush local L2 (release)
    flag = atomicAdd(&ctr[t * 32 + cg], 1);
  }
  __syncthreads();

  if (flag == 7) {
    // closing block: reduce 8 k-block partials, gates, masked update
    __threadfence();                      // invalidate stale L2 (acquire)
    int b0 = tid >> 6;                    // wave id 0..3
    int hl = tid & 63;
#pragma unroll
    for (int bi = 0; bi < 4; bi++) {
      int b = b0 * 4 + bi;
      float z0 = xzt[(size_t)b * G4 + 0 * HH + hu0 + hl];
      float z1 = xzt[(size_t)b * G4 + 1 * HH + hu0 + hl];
      float z2 = xzt[(size_t)b * G4 + 2 * HH + hu0 + hl];
      float z3 = xzt[(size_t)b * G4 + 3 * HH + hu0 + hl];
#pragma unroll
      for (int k2 = 0; k2 < 8; k2++) {
        const float* pp = partial + ((size_t)(k2 * 16 + b)) * G4 + hu0 + hl;
        z0 += pp[0 * HH];
        z1 += pp[1 * HH];
        z2 += pp[2 * HH];
        z3 += pp[3 * HH];
      }
      float ig = 1.f / (1.f + expf(-z0));
      float fg = 1.f / (1.f + expf(-z1));
      float gt = tanhf(z2);
      float og = 1.f / (1.f + expf(-z3));
      int hu = hu0 + hl;
      float c_old = c[(size_t)b * HH + hu];
      float cn = fg * c_old + ig * gt;
      float hn = og * tanhf(cn);
      bool m = tokens[b * TT + t] != 0;
      if (!m) {
        cn = c_old;
        hn = hT_in[(size_t)hu * BB + b];
      }
      c[(size_t)b * HH + hu] = cn;
      hT_out[(size_t)hu * BB + b] = hn;
      allh[((size_t)b * TT + t) * HH + hu] = hn;
    }
  }
}

// ---------------- small-M GEMM for the head: out = XT^T @ W + bias ----------
__global__ __launch_bounds__(256) void smallgemm(
    const float* __restrict__ XT, const float* __restrict__ W,
    const float* __restrict__ bias, float* __restrict__ out,
    int K, int N, int sc, int sb) {
  __shared__ float red[8][16][32];
  int tid = threadIdx.x;
  int kg = tid >> 5;
  int cl = tid & 31;
  int col = blockIdx.x * 32 + cl;
  int kpg = K >> 3;
  float acc[16];
#pragma unroll
  for (int i = 0; i < 16; i++) acc[i] = 0.f;
  if (col < N) {
    const float* Wp = W + (size_t)(kg * kpg) * N + col;
    const float4* x4 = (const float4*)(XT + (size_t)kg * kpg * BB);
    for (int k = 0; k < kpg; k++) {
      float w = Wp[(size_t)k * N];
      float4 a = x4[k * 4 + 0];
      float4 b = x4[k * 4 + 1];
      float4 cc = x4[k * 4 + 2];
      float4 d = x4[k * 4 + 3];
      acc[0]  = fmaf(a.x, w, acc[0]);  acc[1]  = fmaf(a.y, w, acc[1]);
      acc[2]  = fmaf(a.z, w, acc[2]);  acc[3]  = fmaf(a.w, w, acc[3]);
      acc[4]  = fmaf(b.x, w, acc[4]);  acc[5]  = fmaf(b.y, w, acc[5]);
      acc[6]  = fmaf(b.z, w, acc[6]);  acc[7]  = fmaf(b.w, w, acc[7]);
      acc[8]  = fmaf(cc.x, w, acc[8]); acc[9]  = fmaf(cc.y, w, acc[9]);
      acc[10] = fmaf(cc.z, w, acc[10]);acc[11] = fmaf(cc.w, w, acc[11]);
      acc[12] = fmaf(d.x, w, acc[12]); acc[13] = fmaf(d.y, w, acc[13]);
      acc[14] = fmaf(d.z, w, acc[14]); acc[15] = fmaf(d.w, w, acc[15]);
    }
  }
#pragma unroll
  for (int b = 0; b < 16; b++) red[kg][b][cl] = acc[b];
  __syncthreads();
  for (int i = tid; i < 512; i += 256) {
    int b = i >> 5, l = i & 31;
    int cg = blockIdx.x * 32 + l;
    if (cg < N) {
      float s = 0.f;
#pragma unroll
      for (int q = 0; q < 8; q++) s += red[q][b][l];
      out[(size_t)cg * sc + (size_t)b * sb] = s + bias[cg];
    }
  }
}

// ---------------- softmax over rows of [16][1003] ----------------
__global__ __launch_bounds__(256) void softmax_rows(
    const float* __restrict__ logits, float* __restrict__ out, int N) {
  __shared__ float buf[1024];
  __shared__ float wred[4];
  __shared__ float rmax, rsum;
  int b = blockIdx.x, tid = threadIdx.x;
  float m = -1e30f;
  for (int v = tid; v < N; v += 256) {
    float x = logits[(size_t)b * N + v];
    buf[v] = x;
    m = fmaxf(m, x);
  }
  for (int o = 32; o > 0; o >>= 1) m = fmaxf(m, __shfl_down(m, o, 64));
  if ((tid & 63) == 0) wred[tid >> 6] = m;
  __syncthreads();
  if (tid == 0) rmax = fmaxf(fmaxf(wred[0], wred[1]), fmaxf(wred[2], wred[3]));
  __syncthreads();
  float s = 0.f;
  for (int v = tid; v < N; v += 256) {
    float e = expf(buf[v] - rmax);
    buf[v] = e;
    s += e;
  }
  for (int o = 32; o > 0; o >>= 1) s += __shfl_down(s, o, 64);
  if ((tid & 63) == 0) wred[tid >> 6] = s;
  __syncthreads();
  if (tid == 0) rsum = wred[0] + wred[1] + wred[2] + wred[3];
  __syncthreads();
  float inv = 1.f / rsum;
  for (int v = tid; v < N; v += 256) out[(size_t)b * N + v] = buf[v] * inv;
}

extern "C" void kernel_launch(void* const* d_in, const int* in_sizes, int n_in,
                              void* d_out, int out_size, void* d_ws, size_t ws_size,
                              hipStream_t stream) {
  const int*   tokens = (const int*)d_in[0];
  const float* emb  = (const float*)d_in[1];
  const float* W1   = (const float*)d_in[2];
  const float* U1   = (const float*)d_in[3];
  const float* b1   = (const float*)d_in[4];
  const float* W2   = (const float*)d_in[5];
  const float* U2   = (const float*)d_in[6];
  const float* b2   = (const float*)d_in[7];
  const float* W3   = (const float*)d_in[8];
  const float* U3   = (const float*)d_in[9];
  const float* b3   = (const float*)d_in[10];
  const float* Wd1  = (const float*)d_in[11];
  const float* bd1  = (const float*)d_in[12];
  const float* Wd2  = (const float*)d_in[13];
  const float* bd2  = (const float*)d_in[14];
  float* out = (float*)d_out;

  float* ws = (float*)d_ws;
  size_t off = 0;
  float* x_emb = ws + off; off += 51264;
  float* xz    = ws + off; off += (size_t)TT * BB * G4;
  float* allh1 = ws + off; off += (size_t)BB * TT * HH;
  float* allh2 = ws + off; off += (size_t)BB * TT * HH;
  float* allh3 = ws + off; off += (size_t)BB * TT * HH;
  float* hT0   = ws + off; off += HH * BB;
  float* cbuf  = ws + off; off += HH * BB;   // contiguous with hT0
  float* hT1   = ws + off; off += HH * BB;
  float* yT    = ws + off; off += HH * BB;
  float* logits = ws + off; off += 16384;
  float* partial = ws + off; off += (size_t)8 * BB * G4;  // 4 MB
  int*   ctr   = (int*)(ws + off); off += 1024;

  float* hping[2] = {hT0, hT1};

  const float* Ws[3] = {W1, W2, W3};
  const float* Us[3] = {U1, U2, U3};
  const float* bs[3] = {b1, b2, b3};
  float* allhs[3] = {allh1, allh2, allh3};
  const float* Xs[3] = {x_emb, allh1, allh2};
  int Ks[3] = {EE, HH, HH};

  embed_kernel<<<dim3((BB * TT * EE + 255) / 256), 256, 0, stream>>>(tokens, emb, x_emb);

  for (int layer = 0; layer < 3; layer++) {
    gemm_xz<<<dim3(G4 / 128, (BB * TT) / 64), 256, 0, stream>>>(
        Xs[layer], Ks[layer], Ws[layer], bs[layer], xz);
    (void)hipMemsetAsync(hT0, 0, 2 * HH * BB * sizeof(float), stream);  // hT0 + cbuf
    (void)hipMemsetAsync(ctr, 0, TT * 32 * sizeof(int), stream);
    for (int t = 0; t < TT; t++) {
      lstm_step<<<dim3(256), 256, 0, stream>>>(
          Us[layer], xz + (size_t)t * BB * G4, hping[t & 1], hping[(t + 1) & 1],
          cbuf, allhs[layer], tokens, t, partial, ctr);
    }
  }

  smallgemm<<<dim3(HH / 32), 256, 0, stream>>>(hT0, Wd1, bd1, yT, HH, HH, 16, 1);
  smallgemm<<<dim3((VV + 31) / 32), 256, 0, stream>>>(yT, Wd2, bd2, logits, HH, VV, 1, VV);
  softmax_rows<<<dim3(BB), 256, 0, stream>>>(logits, out, VV);
}

// Round 3
// 3239.984 us; speedup vs baseline: 2.7003x; 1.2378x over previous
//
#include <hip/hip_runtime.h>
#include <hip/hip_bf16.h>
#include <cstddef>

#define BB 16
#define TT 32
#define VV 1003
#define EE 100
#define HH 2048
#define G4 8192  // 4*H

typedef __attribute__((ext_vector_type(8))) short s16x8;
typedef __attribute__((ext_vector_type(4))) float f32x4;

__device__ __forceinline__ unsigned short f2bf(float f) {
  unsigned u = __float_as_uint(f);
  u += 0x7fffu + ((u >> 16) & 1u);
  return (unsigned short)(u >> 16);
}
__device__ __forceinline__ float bf2f(unsigned short s) {
  return __uint_as_float(((unsigned)s) << 16);
}

// ---------------- embedding gather -> A-fragments (hi/lo bf16) ----------------
// x_frag layout per t: [hi: [4 kt][64 lane][8]] [lo: same] (t_stride=4096 shorts)
__global__ __launch_bounds__(256) void embed_frag(
    const int* __restrict__ tokens, const float* __restrict__ emb,
    short* __restrict__ xf) {
  int i = blockIdx.x * 256 + threadIdx.x;   // 32t * 16b * 128e
  if (i >= TT * BB * 128) return;
  int e = i & 127, b = (i >> 7) & 15, t = i >> 11;
  float v = 0.f;
  if (e < EE) v = emb[(size_t)tokens[b * TT + t] * EE + e];
  unsigned short hi = f2bf(v);
  unsigned short lo = f2bf(v - bf2f(hi));
  int kt = e >> 5, kk = e & 31;
  int lane = (kk >> 3) * 16 + b, j = kk & 7;
  size_t idx = (size_t)t * 4096 + ((size_t)kt * 64 + lane) * 8 + j;
  xf[idx] = (short)hi;
  xf[idx + 2048] = (short)lo;
}

// ---------------- MFMA GEMM: xz[t][b][col] = A[t*16+b][:] @ W + bias --------
// A given as bf16 hi/lo fragments. grid = (N/128, 4): block tile M=128(8 t) x N=128.
// 4 waves; wave w owns t-tiles {t0+2w, t0+2w+1} x all 8 n-tiles.
__global__ __launch_bounds__(256) void gemm_mfma(
    const short* __restrict__ af, int lo_off, int t_stride, int nkt, int Kreal,
    const float* __restrict__ W, const float* __restrict__ bias,
    float* __restrict__ xz) {
  __shared__ __align__(16) short Bs_hi[8 * 64 * 8];  // [nt][lane][8]
  __shared__ __align__(16) short Bs_lo[8 * 64 * 8];
  int tid = threadIdx.x;
  int w = tid >> 6, L = tid & 63;
  int col0 = blockIdx.x * 128;
  int t_a = blockIdx.y * 8 + w * 2;
  int c = tid & 127, kgrp = tid >> 7;  // staging role: col c, k-rows kgrp*16..+15

  f32x4 acc0[8], acc1[8];
#pragma unroll
  for (int nt = 0; nt < 8; nt++) {
    acc0[nt] = (f32x4){0.f, 0.f, 0.f, 0.f};
    acc1[nt] = (f32x4){0.f, 0.f, 0.f, 0.f};
  }
  const short* Ah = af + (size_t)t_a * t_stride + L * 8;

  for (int kt = 0; kt < nkt; kt++) {
    // load W rows (fp32, coalesced across 128 cols)
    float v[16];
    int k0 = kt * 32 + kgrp * 16;
#pragma unroll
    for (int r = 0; r < 16; r++) {
      int gk = k0 + r;
      v[r] = (gk < Kreal) ? W[(size_t)gk * G4 + col0 + c] : 0.f;
    }
    __syncthreads();  // previous tile's reads done
#pragma unroll
    for (int run = 0; run < 2; run++) {
      s16x8 hh, ll;
#pragma unroll
      for (int j = 0; j < 8; j++) {
        float f = v[run * 8 + j];
        unsigned short h = f2bf(f);
        hh[j] = (short)h;
        ll[j] = (short)f2bf(f - bf2f(h));
      }
      int lane2 = kgrp * 32 + run * 16 + (c & 15);
      int nt = c >> 4;
      *(s16x8*)&Bs_hi[(nt * 64 + lane2) * 8] = hh;
      *(s16x8*)&Bs_lo[(nt * 64 + lane2) * 8] = ll;
    }
    __syncthreads();

    s16x8 aH0 = *(const s16x8*)(Ah + kt * 512);
    s16x8 aL0 = *(const s16x8*)(Ah + lo_off + kt * 512);
    s16x8 aH1 = *(const s16x8*)(Ah + t_stride + kt * 512);
    s16x8 aL1 = *(const s16x8*)(Ah + t_stride + lo_off + kt * 512);
#pragma unroll
    for (int nt = 0; nt < 8; nt++) {
      s16x8 bH = *(const s16x8*)&Bs_hi[(nt * 64 + L) * 8];
      s16x8 bL = *(const s16x8*)&Bs_lo[(nt * 64 + L) * 8];
      acc0[nt] = __builtin_amdgcn_mfma_f32_16x16x32_bf16(aH0, bH, acc0[nt], 0, 0, 0);
      acc0[nt] = __builtin_amdgcn_mfma_f32_16x16x32_bf16(aL0, bH, acc0[nt], 0, 0, 0);
      acc0[nt] = __builtin_amdgcn_mfma_f32_16x16x32_bf16(aH0, bL, acc0[nt], 0, 0, 0);
      acc1[nt] = __builtin_amdgcn_mfma_f32_16x16x32_bf16(aH1, bH, acc1[nt], 0, 0, 0);
      acc1[nt] = __builtin_amdgcn_mfma_f32_16x16x32_bf16(aL1, bH, acc1[nt], 0, 0, 0);
      acc1[nt] = __builtin_amdgcn_mfma_f32_16x16x32_bf16(aH1, bL, acc1[nt], 0, 0, 0);
    }
  }

  int nq = L >> 4, hl = L & 15;  // D: col=hl, row b = nq*4+r
#pragma unroll
  for (int nt = 0; nt < 8; nt++) {
    int colg = col0 + nt * 16 + hl;
    float bv = bias[colg];
#pragma unroll
    for (int r = 0; r < 4; r++) {
      int b = nq * 4 + r;
      xz[((size_t)t_a * 16 + b) * G4 + colg] = acc0[nt][r] + bv;
      xz[((size_t)(t_a + 1) * 16 + b) * G4 + colg] = acc1[nt][r] + bv;
    }
  }
}

// ---------------- one LSTM step, fully fused, MFMA bf16x3 --------------------
// grid 128 (16 hidden units each), 512 threads = 8 waves (gate g = w&3, khalf = w>>2)
// h fragments: slot layout [hi: [64 kt][64 lane][8]] [lo] (slot = 65536 shorts)
__global__ __launch_bounds__(512) void lstm_step(
    const float* __restrict__ U,       // [2048][8192]
    const float* __restrict__ xzt,     // [16][8192]
    const short* __restrict__ hf_in,   // slot t
    short* __restrict__ hf_out,        // slot t+1
    const float* __restrict__ hT_in,   // [2048][16] fp32
    float* __restrict__ hT_out,
    float* __restrict__ c,             // [16][2048]
    const int* __restrict__ tokens, int t) {
  __shared__ float red[4][64][4];
  __shared__ float zs[4][16][16];
  int tid = threadIdx.x, w = tid >> 6, L = tid & 63;
  int g = w & 3, kh = w >> 2;
  int hu0 = blockIdx.x * 16;
  size_t colb = (size_t)g * HH + hu0 + (L & 15);

  f32x4 acc = {0.f, 0.f, 0.f, 0.f};
  const float* Ub = U + ((size_t)kh * 1024 + (size_t)(L >> 4) * 8) * G4 + colb;
  const short* Hh = hf_in + (kh * 32) * 512 + L * 8;

#pragma unroll 2
  for (int i = 0; i < 32; i++) {
    s16x8 ah = *(const s16x8*)(Hh + i * 512);
    s16x8 al = *(const s16x8*)(Hh + 32768 + i * 512);
    const float* Ui = Ub + (size_t)i * 32 * G4;
    s16x8 bh, bl;
#pragma unroll
    for (int j = 0; j < 8; j++) {
      float u = Ui[(size_t)j * G4];
      unsigned short h = f2bf(u);
      bh[j] = (short)h;
      bl[j] = (short)f2bf(u - bf2f(h));
    }
    acc = __builtin_amdgcn_mfma_f32_16x16x32_bf16(ah, bh, acc, 0, 0, 0);
    acc = __builtin_amdgcn_mfma_f32_16x16x32_bf16(al, bh, acc, 0, 0, 0);
    acc = __builtin_amdgcn_mfma_f32_16x16x32_bf16(ah, bl, acc, 0, 0, 0);
  }

  if (kh == 1) *(f32x4*)&red[g][L][0] = acc;
  __syncthreads();
  if (kh == 0) {
    f32x4 o = *(const f32x4*)&red[g][L][0];
    acc += o;
#pragma unroll
    for (int r = 0; r < 4; r++) zs[g][(L >> 4) * 4 + r][L & 15] = acc[r];
  }
  __syncthreads();

  if (tid < 256) {
    int b = tid >> 4, hl = tid & 15;
    int hu = hu0 + hl;
    float z0 = zs[0][b][hl] + xzt[(size_t)b * G4 + 0 * HH + hu];
    float z1 = zs[1][b][hl] + xzt[(size_t)b * G4 + 1 * HH + hu];
    float z2 = zs[2][b][hl] + xzt[(size_t)b * G4 + 2 * HH + hu];
    float z3 = zs[3][b][hl] + xzt[(size_t)b * G4 + 3 * HH + hu];
    float ig = 1.f / (1.f + expf(-z0));
    float fg = 1.f / (1.f + expf(-z1));
    float gt = tanhf(z2);
    float og = 1.f / (1.f + expf(-z3));
    float c_old = c[(size_t)b * HH + hu];
    float cn = fg * c_old + ig * gt;
    float hn = og * tanhf(cn);
    if (tokens[b * TT + t] == 0) {
      cn = c_old;
      hn = hT_in[(size_t)hu * BB + b];
    }
    c[(size_t)b * HH + hu] = cn;
    hT_out[(size_t)hu * BB + b] = hn;
    unsigned short hi = f2bf(hn);
    unsigned short lo = f2bf(hn - bf2f(hi));
    int kt = hu >> 5, kk = hu & 31;
    int lane2 = (kk >> 3) * 16 + b, j = kk & 7;
    size_t idx = ((size_t)kt * 64 + lane2) * 8 + j;
    hf_out[idx] = (short)hi;
    hf_out[idx + 32768] = (short)lo;
  }
}

// ---------------- small-M GEMM for the head: out = XT^T @ W + bias ----------
__global__ __launch_bounds__(256) void smallgemm(
    const float* __restrict__ XT, const float* __restrict__ W,
    const float* __restrict__ bias, float* __restrict__ out,
    int K, int N, int sc, int sb) {
  __shared__ float red[8][16][32];
  int tid = threadIdx.x;
  int kg = tid >> 5;
  int cl = tid & 31;
  int col = blockIdx.x * 32 + cl;
  int kpg = K >> 3;
  float acc[16];
#pragma unroll
  for (int i = 0; i < 16; i++) acc[i] = 0.f;
  if (col < N) {
    const float* Wp = W + (size_t)(kg * kpg) * N + col;
    const float4* x4 = (const float4*)(XT + (size_t)kg * kpg * BB);
    for (int k = 0; k < kpg; k++) {
      float w = Wp[(size_t)k * N];
      float4 a = x4[k * 4 + 0];
      float4 b = x4[k * 4 + 1];
      float4 cc = x4[k * 4 + 2];
      float4 d = x4[k * 4 + 3];
      acc[0]  = fmaf(a.x, w, acc[0]);  acc[1]  = fmaf(a.y, w, acc[1]);
      acc[2]  = fmaf(a.z, w, acc[2]);  acc[3]  = fmaf(a.w, w, acc[3]);
      acc[4]  = fmaf(b.x, w, acc[4]);  acc[5]  = fmaf(b.y, w, acc[5]);
      acc[6]  = fmaf(b.z, w, acc[6]);  acc[7]  = fmaf(b.w, w, acc[7]);
      acc[8]  = fmaf(cc.x, w, acc[8]); acc[9]  = fmaf(cc.y, w, acc[9]);
      acc[10] = fmaf(cc.z, w, acc[10]);acc[11] = fmaf(cc.w, w, acc[11]);
      acc[12] = fmaf(d.x, w, acc[12]); acc[13] = fmaf(d.y, w, acc[13]);
      acc[14] = fmaf(d.z, w, acc[14]); acc[15] = fmaf(d.w, w, acc[15]);
    }
  }
#pragma unroll
  for (int b = 0; b < 16; b++) red[kg][b][cl] = acc[b];
  __syncthreads();
  for (int i = tid; i < 512; i += 256) {
    int b = i >> 5, l = i & 31;
    int cg = blockIdx.x * 32 + l;
    if (cg < N) {
      float s = 0.f;
#pragma unroll
      for (int q = 0; q < 8; q++) s += red[q][b][l];
      out[(size_t)cg * sc + (size_t)b * sb] = s + bias[cg];
    }
  }
}

// ---------------- softmax over rows of [16][1003] ----------------
__global__ __launch_bounds__(256) void softmax_rows(
    const float* __restrict__ logits, float* __restrict__ out, int N) {
  __shared__ float buf[1024];
  __shared__ float wred[4];
  __shared__ float rmax, rsum;
  int b = blockIdx.x, tid = threadIdx.x;
  float m = -1e30f;
  for (int v = tid; v < N; v += 256) {
    float x = logits[(size_t)b * N + v];
    buf[v] = x;
    m = fmaxf(m, x);
  }
  for (int o = 32; o > 0; o >>= 1) m = fmaxf(m, __shfl_down(m, o, 64));
  if ((tid & 63) == 0) wred[tid >> 6] = m;
  __syncthreads();
  if (tid == 0) rmax = fmaxf(fmaxf(wred[0], wred[1]), fmaxf(wred[2], wred[3]));
  __syncthreads();
  float s = 0.f;
  for (int v = tid; v < N; v += 256) {
    float e = expf(buf[v] - rmax);
    buf[v] = e;
    s += e;
  }
  for (int o = 32; o > 0; o >>= 1) s += __shfl_down(s, o, 64);
  if ((tid & 63) == 0) wred[tid >> 6] = s;
  __syncthreads();
  if (tid == 0) rsum = wred[0] + wred[1] + wred[2] + wred[3];
  __syncthreads();
  float inv = 1.f / rsum;
  for (int v = tid; v < N; v += 256) out[(size_t)b * N + v] = buf[v] * inv;
}

extern "C" void kernel_launch(void* const* d_in, const int* in_sizes, int n_in,
                              void* d_out, int out_size, void* d_ws, size_t ws_size,
                              hipStream_t stream) {
  const int*   tokens = (const int*)d_in[0];
  const float* emb  = (const float*)d_in[1];
  const float* W1   = (const float*)d_in[2];
  const float* U1   = (const float*)d_in[3];
  const float* b1   = (const float*)d_in[4];
  const float* W2   = (const float*)d_in[5];
  const float* U2   = (const float*)d_in[6];
  const float* b2   = (const float*)d_in[7];
  const float* W3   = (const float*)d_in[8];
  const float* U3   = (const float*)d_in[9];
  const float* b3   = (const float*)d_in[10];
  const float* Wd1  = (const float*)d_in[11];
  const float* bd1  = (const float*)d_in[12];
  const float* Wd2  = (const float*)d_in[13];
  const float* bd2  = (const float*)d_in[14];
  float* out = (float*)d_out;

  char* base = (char*)d_ws;
  size_t off = 0;
  auto carve = [&](size_t bytes) -> char* {
    char* p = base + off;
    off += (bytes + 255) & ~(size_t)255;
    return p;
  };
  float* xz      = (float*)carve((size_t)TT * BB * G4 * 4);   // 16 MB
  short* allhf0  = (short*)carve(33ull * 65536 * 2);          // 4.33 MB
  short* allhf1  = (short*)carve(33ull * 65536 * 2);
  short* allhf2  = (short*)carve(33ull * 65536 * 2);
  short* xfrag   = (short*)carve((size_t)TT * 4096 * 2);      // 256 KB
  float* hT0     = (float*)carve(2 * HH * BB * 4);            // hT0 + c contiguous
  float* cbuf    = hT0 + HH * BB;
  float* hT1     = (float*)carve(HH * BB * 4);
  float* yT      = (float*)carve(HH * BB * 4);
  float* logits  = (float*)carve(BB * 1024 * 4);

  short* allhf[3] = {allhf0, allhf1, allhf2};
  const float* Us[3] = {U1, U2, U3};
  const float* Ws[3] = {W1, W2, W3};
  const float* bs[3] = {b1, b2, b3};
  float* hping[2] = {hT0, hT1};

  embed_frag<<<dim3(256), 256, 0, stream>>>(tokens, emb, xfrag);

  for (int layer = 0; layer < 3; layer++) {
    // A-fragments for the xz GEMM
    const short* af;
    int lo_off, t_stride, nkt, Kreal;
    if (layer == 0) {
      af = xfrag; lo_off = 2048; t_stride = 4096; nkt = 4; Kreal = EE;
    } else {
      af = allhf[layer - 1] + 65536;  // slot 1 == h at t=0
      lo_off = 32768; t_stride = 65536; nkt = 64; Kreal = HH;
    }
    gemm_mfma<<<dim3(G4 / 128, 4), 256, 0, stream>>>(
        af, lo_off, t_stride, nkt, Kreal, Ws[layer], bs[layer], xz);

    (void)hipMemsetAsync(allhf[layer], 0, 65536 * 2, stream);       // slot 0
    (void)hipMemsetAsync(hT0, 0, 2 * HH * BB * 4, stream);          // hT0 + c
    for (int t = 0; t < TT; t++) {
      lstm_step<<<dim3(128), 512, 0, stream>>>(
          Us[layer], xz + (size_t)t * BB * G4,
          allhf[layer] + (size_t)t * 65536, allhf[layer] + (size_t)(t + 1) * 65536,
          hping[t & 1], hping[(t + 1) & 1], cbuf, tokens, t);
    }
  }

  // final h (t=31) is in hT0
  smallgemm<<<dim3(HH / 32), 256, 0, stream>>>(hT0, Wd1, bd1, yT, HH, HH, 16, 1);
  smallgemm<<<dim3((VV + 31) / 32), 256, 0, stream>>>(yT, Wd2, bd2, logits, HH, VV, 1, VV);
  softmax_rows<<<dim3(BB), 256, 0, stream>>>(logits, out, VV);
}

// Round 4
// 1843.953 us; speedup vs baseline: 4.7447x; 1.7571x over previous
//
#include <hip/hip_runtime.h>
#include <hip/hip_bf16.h>
#include <cstddef>

#define BB 16
#define TT 32
#define VV 1003
#define EE 100
#define HH 2048
#define G4 8192  // 4*H

typedef __attribute__((ext_vector_type(8))) short s16x8;
typedef __attribute__((ext_vector_type(4))) float f32x4;

__device__ __forceinline__ unsigned short f2bf(float f) {
  unsigned u = __float_as_uint(f);
  u += 0x7fffu + ((u >> 16) & 1u);
  return (unsigned short)(u >> 16);
}
__device__ __forceinline__ float bf2f(unsigned short s) {
  return __uint_as_float(((unsigned)s) << 16);
}

// ---------------- embedding gather -> A-fragments (hi/lo bf16) ---------------
// xf layout per t: [kt 0..3][lane][8] hi, then lo at +2048 (t stride 4096 shorts)
__global__ __launch_bounds__(256) void embed_frag(
    const int* __restrict__ tokens, const float* __restrict__ emb,
    short* __restrict__ xf) {
  int i = blockIdx.x * 256 + threadIdx.x;   // 32t * 16b * 128e
  if (i >= TT * BB * 128) return;
  int e = i & 127, b = (i >> 7) & 15, t = i >> 11;
  float v = 0.f;
  if (e < EE) v = emb[(size_t)tokens[b * TT + t] * EE + e];
  unsigned short hi = f2bf(v);
  unsigned short lo = f2bf(v - bf2f(hi));
  int kt = e >> 5, kk = e & 31;
  int lane = (kk >> 3) * 16 + b, j = kk & 7;
  size_t idx = (size_t)t * 4096 + ((size_t)kt * 64 + lane) * 8 + j;
  xf[idx] = (short)hi;
  xf[idx + 2048] = (short)lo;
}

// ---------------- pre-split fp32 matrix -> permuted B-fragments --------------
// src [Kreal][8192]. Tile ct (0..511) covers global cols g*2048 + ct*4 + hq
// (cl = g*4+hq, g=gate, hq=0..3). Frag (ct,kt): 512 shorts hi + 512 lo.
// dst[((ct*nkt)+kt)*1024 + lane*8 + j], lane=(krem>>3)*16+cl, k=kt*32+krem.
__global__ __launch_bounds__(256) void split_matrix(
    const float* __restrict__ src, short* __restrict__ dst,
    int Kreal, int nkt, int sh) {
  int tid = threadIdx.x, w = tid >> 6, L = tid & 63;
  int tile = blockIdx.x * 4 + w;
  int ct = tile >> sh, kt = tile & (nkt - 1);
  int cl = L & 15;
  int gcol = (cl >> 2) * HH + ct * 4 + (cl & 3);
  int r0 = kt * 32 + (L >> 4) * 8;
  s16x8 hh, ll;
#pragma unroll
  for (int j = 0; j < 8; j++) {
    int r = r0 + j;
    float v = (r < Kreal) ? src[(size_t)r * G4 + gcol] : 0.f;
    unsigned short h = f2bf(v);
    hh[j] = (short)h;
    ll[j] = (short)f2bf(v - bf2f(h));
  }
  size_t base = ((size_t)tile) * 1024 + L * 8;   // tile = ct*nkt+kt exactly
  *(s16x8*)&dst[base] = hh;
  *(s16x8*)&dst[base + 512] = ll;
}

// ---------------- MFMA GEMM: xz (permuted cols) = A @ W + bias --------------
// A bf16 hi/lo fragments; W pre-split frags. grid (64, 4): N-tile 128 (8 ct),
// M-tile 128 (8 t). 4 waves; wave w owns t-tiles {t0+2w, t0+2w+1}.
__global__ __launch_bounds__(256) void gemm_mfma(
    const short* __restrict__ af, int lo_off, int t_stride, int nkt,
    const short* __restrict__ wfrag, const float* __restrict__ bias,
    float* __restrict__ xz) {
  __shared__ __align__(16) short Bs[8][1024];
  int tid = threadIdx.x;
  int w = tid >> 6, L = tid & 63;
  int ct0 = blockIdx.x * 8;
  int t_a = blockIdx.y * 8 + w * 2;

  f32x4 acc0[8], acc1[8];
#pragma unroll
  for (int nt = 0; nt < 8; nt++) {
    acc0[nt] = (f32x4){0.f, 0.f, 0.f, 0.f};
    acc1[nt] = (f32x4){0.f, 0.f, 0.f, 0.f};
  }
  const short* Ah = af + (size_t)t_a * t_stride + L * 8;

  for (int kt = 0; kt < nkt; kt++) {
    s16x8 tmp[4];
#pragma unroll
    for (int q = 0; q < 4; q++) {
      int chunk = q * 256 + tid;
      int nt = chunk >> 7, idx = chunk & 127;
      tmp[q] = *(const s16x8*)&wfrag[((size_t)(ct0 + nt) * nkt + kt) * 1024 + idx * 8];
    }
    __syncthreads();
#pragma unroll
    for (int q = 0; q < 4; q++) {
      int chunk = q * 256 + tid;
      int nt = chunk >> 7, idx = chunk & 127;
      *(s16x8*)&Bs[nt][idx * 8] = tmp[q];
    }
    __syncthreads();

    s16x8 aH0 = *(const s16x8*)(Ah + kt * 512);
    s16x8 aL0 = *(const s16x8*)(Ah + lo_off + kt * 512);
    s16x8 aH1 = *(const s16x8*)(Ah + t_stride + kt * 512);
    s16x8 aL1 = *(const s16x8*)(Ah + t_stride + lo_off + kt * 512);
#pragma unroll
    for (int nt = 0; nt < 8; nt++) {
      s16x8 bH = *(const s16x8*)&Bs[nt][L * 8];
      s16x8 bL = *(const s16x8*)&Bs[nt][512 + L * 8];
      acc0[nt] = __builtin_amdgcn_mfma_f32_16x16x32_bf16(aH0, bH, acc0[nt], 0, 0, 0);
      acc0[nt] = __builtin_amdgcn_mfma_f32_16x16x32_bf16(aL0, bH, acc0[nt], 0, 0, 0);
      acc0[nt] = __builtin_amdgcn_mfma_f32_16x16x32_bf16(aH0, bL, acc0[nt], 0, 0, 0);
      acc1[nt] = __builtin_amdgcn_mfma_f32_16x16x32_bf16(aH1, bH, acc1[nt], 0, 0, 0);
      acc1[nt] = __builtin_amdgcn_mfma_f32_16x16x32_bf16(aL1, bH, acc1[nt], 0, 0, 0);
      acc1[nt] = __builtin_amdgcn_mfma_f32_16x16x32_bf16(aH1, bL, acc1[nt], 0, 0, 0);
    }
  }

  int nq = L >> 4, hl = L & 15;
#pragma unroll
  for (int nt = 0; nt < 8; nt++) {
    int ctg = ct0 + nt;
    int gcol = (hl >> 2) * HH + ctg * 4 + (hl & 3);
    float bv = bias[gcol];
#pragma unroll
    for (int r = 0; r < 4; r++) {
      int b = nq * 4 + r;
      xz[((size_t)t_a * 16 + b) * G4 + ctg * 16 + hl] = acc0[nt][r] + bv;
      xz[((size_t)(t_a + 1) * 16 + b) * G4 + ctg * 16 + hl] = acc1[nt][r] + bv;
    }
  }
}

// ---------------- one LSTM step, fused, pre-split U frags --------------------
// grid 512 (1 col-tile = 4 hu x 4 gates each), 256 thr = 4 waves (K-quarters).
__global__ __launch_bounds__(256) void lstm_step(
    const short* __restrict__ Ufrag,   // pre-split, permuted tiles
    const float* __restrict__ xzt,     // [16][8192] permuted cols
    const short* __restrict__ hf_in,   // slot t  (A-frags)
    short* __restrict__ hf_out,        // slot t+1
    const float* __restrict__ hT_in,   // [2048][16] fp32
    float* __restrict__ hT_out,
    float* __restrict__ c,             // [16][2048]
    const int* __restrict__ tokens, int t) {
  __shared__ float red[4][16][16];
  __shared__ float zs[16][16];
  int tid = threadIdx.x, w = tid >> 6, L = tid & 63;
  int ct = blockIdx.x;

  f32x4 acc = {0.f, 0.f, 0.f, 0.f};
  const short* Ub = Ufrag + ((size_t)ct * 64 + w * 16) * 1024 + L * 8;
  const short* Hb = hf_in + (w * 16) * 512 + L * 8;

#pragma unroll 4
  for (int i = 0; i < 16; i++) {
    s16x8 bh = *(const s16x8*)(Ub + i * 1024);
    s16x8 bl = *(const s16x8*)(Ub + i * 1024 + 512);
    s16x8 ah = *(const s16x8*)(Hb + i * 512);
    s16x8 al = *(const s16x8*)(Hb + i * 512 + 32768);
    acc = __builtin_amdgcn_mfma_f32_16x16x32_bf16(ah, bh, acc, 0, 0, 0);
    acc = __builtin_amdgcn_mfma_f32_16x16x32_bf16(al, bh, acc, 0, 0, 0);
    acc = __builtin_amdgcn_mfma_f32_16x16x32_bf16(ah, bl, acc, 0, 0, 0);
  }
#pragma unroll
  for (int r = 0; r < 4; r++) red[w][(L >> 4) * 4 + r][L & 15] = acc[r];
  __syncthreads();

  {
    int b = tid >> 4, cl = tid & 15;
    zs[b][cl] = red[0][b][cl] + red[1][b][cl] + red[2][b][cl] + red[3][b][cl]
              + xzt[(size_t)b * G4 + ct * 16 + cl];
  }
  __syncthreads();

  if (tid < 64) {
    int b = tid >> 2, hq = tid & 3;
    int hu = ct * 4 + hq;
    float z0 = zs[b][0 * 4 + hq];
    float z1 = zs[b][1 * 4 + hq];
    float z2 = zs[b][2 * 4 + hq];
    float z3 = zs[b][3 * 4 + hq];
    float ig = 1.f / (1.f + expf(-z0));
    float fg = 1.f / (1.f + expf(-z1));
    float gt = tanhf(z2);
    float og = 1.f / (1.f + expf(-z3));
    float c_old = c[(size_t)b * HH + hu];
    float cn = fg * c_old + ig * gt;
    float hn = og * tanhf(cn);
    if (tokens[b * TT + t] == 0) {
      cn = c_old;
      hn = hT_in[(size_t)hu * BB + b];
    }
    c[(size_t)b * HH + hu] = cn;
    hT_out[(size_t)hu * BB + b] = hn;
    unsigned short hi = f2bf(hn);
    unsigned short lo = f2bf(hn - bf2f(hi));
    int kt2 = hu >> 5, kk = hu & 31;
    int lane2 = (kk >> 3) * 16 + b, jj = kk & 7;
    size_t idx = ((size_t)kt2 * 64 + lane2) * 8 + jj;
    hf_out[idx] = (short)hi;
    hf_out[idx + 32768] = (short)lo;
  }
}

// ---------------- small-M GEMM for the head: out = XT^T @ W + bias ----------
__global__ __launch_bounds__(256) void smallgemm(
    const float* __restrict__ XT, const float* __restrict__ W,
    const float* __restrict__ bias, float* __restrict__ out,
    int K, int N, int sc, int sb) {
  __shared__ float red[8][16][32];
  int tid = threadIdx.x;
  int kg = tid >> 5;
  int cl = tid & 31;
  int col = blockIdx.x * 32 + cl;
  int kpg = K >> 3;
  float acc[16];
#pragma unroll
  for (int i = 0; i < 16; i++) acc[i] = 0.f;
  if (col < N) {
    const float* Wp = W + (size_t)(kg * kpg) * N + col;
    const float4* x4 = (const float4*)(XT + (size_t)kg * kpg * BB);
    for (int k = 0; k < kpg; k++) {
      float w = Wp[(size_t)k * N];
      float4 a = x4[k * 4 + 0];
      float4 b = x4[k * 4 + 1];
      float4 cc = x4[k * 4 + 2];
      float4 d = x4[k * 4 + 3];
      acc[0]  = fmaf(a.x, w, acc[0]);  acc[1]  = fmaf(a.y, w, acc[1]);
      acc[2]  = fmaf(a.z, w, acc[2]);  acc[3]  = fmaf(a.w, w, acc[3]);
      acc[4]  = fmaf(b.x, w, acc[4]);  acc[5]  = fmaf(b.y, w, acc[5]);
      acc[6]  = fmaf(b.z, w, acc[6]);  acc[7]  = fmaf(b.w, w, acc[7]);
      acc[8]  = fmaf(cc.x, w, acc[8]); acc[9]  = fmaf(cc.y, w, acc[9]);
      acc[10] = fmaf(cc.z, w, acc[10]);acc[11] = fmaf(cc.w, w, acc[11]);
      acc[12] = fmaf(d.x, w, acc[12]); acc[13] = fmaf(d.y, w, acc[13]);
      acc[14] = fmaf(d.z, w, acc[14]); acc[15] = fmaf(d.w, w, acc[15]);
    }
  }
#pragma unroll
  for (int b = 0; b < 16; b++) red[kg][b][cl] = acc[b];
  __syncthreads();
  for (int i = tid; i < 512; i += 256) {
    int b = i >> 5, l = i & 31;
    int cg = blockIdx.x * 32 + l;
    if (cg < N) {
      float s = 0.f;
#pragma unroll
      for (int q = 0; q < 8; q++) s += red[q][b][l];
      out[(size_t)cg * sc + (size_t)b * sb] = s + bias[cg];
    }
  }
}

// ---------------- softmax over rows of [16][1003] ----------------
__global__ __launch_bounds__(256) void softmax_rows(
    const float* __restrict__ logits, float* __restrict__ out, int N) {
  __shared__ float buf[1024];
  __shared__ float wred[4];
  __shared__ float rmax, rsum;
  int b = blockIdx.x, tid = threadIdx.x;
  float m = -1e30f;
  for (int v = tid; v < N; v += 256) {
    float x = logits[(size_t)b * N + v];
    buf[v] = x;
    m = fmaxf(m, x);
  }
  for (int o = 32; o > 0; o >>= 1) m = fmaxf(m, __shfl_down(m, o, 64));
  if ((tid & 63) == 0) wred[tid >> 6] = m;
  __syncthreads();
  if (tid == 0) rmax = fmaxf(fmaxf(wred[0], wred[1]), fmaxf(wred[2], wred[3]));
  __syncthreads();
  float s = 0.f;
  for (int v = tid; v < N; v += 256) {
    float e = expf(buf[v] - rmax);
    buf[v] = e;
    s += e;
  }
  for (int o = 32; o > 0; o >>= 1) s += __shfl_down(s, o, 64);
  if ((tid & 63) == 0) wred[tid >> 6] = s;
  __syncthreads();
  if (tid == 0) rsum = wred[0] + wred[1] + wred[2] + wred[3];
  __syncthreads();
  float inv = 1.f / rsum;
  for (int v = tid; v < N; v += 256) out[(size_t)b * N + v] = buf[v] * inv;
}

extern "C" void kernel_launch(void* const* d_in, const int* in_sizes, int n_in,
                              void* d_out, int out_size, void* d_ws, size_t ws_size,
                              hipStream_t stream) {
  const int*   tokens = (const int*)d_in[0];
  const float* emb  = (const float*)d_in[1];
  const float* W1   = (const float*)d_in[2];
  const float* U1   = (const float*)d_in[3];
  const float* b1   = (const float*)d_in[4];
  const float* W2   = (const float*)d_in[5];
  const float* U2   = (const float*)d_in[6];
  const float* b2   = (const float*)d_in[7];
  const float* W3   = (const float*)d_in[8];
  const float* U3   = (const float*)d_in[9];
  const float* b3   = (const float*)d_in[10];
  const float* Wd1  = (const float*)d_in[11];
  const float* bd1  = (const float*)d_in[12];
  const float* Wd2  = (const float*)d_in[13];
  const float* bd2  = (const float*)d_in[14];
  float* out = (float*)d_out;

  char* base = (char*)d_ws;
  size_t off = 0;
  auto carve = [&](size_t bytes) -> char* {
    char* p = base + off;
    off += (bytes + 255) & ~(size_t)255;
    return p;
  };
  float* xz      = (float*)carve((size_t)TT * BB * G4 * 4);     // 16 MB
  short* allhf0  = (short*)carve(33ull * 65536 * 2);            // 4.33 MB
  short* allhf1  = (short*)carve(33ull * 65536 * 2);
  short* allhf2  = (short*)carve(33ull * 65536 * 2);
  short* xfrag   = (short*)carve((size_t)TT * 4096 * 2);        // 256 KB
  short* frag    = (short*)carve(512ull * 64 * 1024 * 2);       // 64 MB shared W/U frags
  float* hT0     = (float*)carve(2 * HH * BB * 4);              // hT0 + c contiguous
  float* cbuf    = hT0 + HH * BB;
  float* hT1     = (float*)carve(HH * BB * 4);
  float* yT      = (float*)carve(HH * BB * 4);
  float* logits  = (float*)carve(BB * 1024 * 4);

  short* allhf[3] = {allhf0, allhf1, allhf2};
  const float* Us[3] = {U1, U2, U3};
  const float* Ws[3] = {W1, W2, W3};
  const float* bs[3] = {b1, b2, b3};
  float* hping[2] = {hT0, hT1};

  embed_frag<<<dim3(256), 256, 0, stream>>>(tokens, emb, xfrag);

  for (int layer = 0; layer < 3; layer++) {
    const short* af;
    int lo_off, t_stride, nktW, KrealW;
    if (layer == 0) {
      af = xfrag; lo_off = 2048; t_stride = 4096; nktW = 4; KrealW = EE;
    } else {
      af = allhf[layer - 1] + 65536;  // slot 1 == h at t=0
      lo_off = 32768; t_stride = 65536; nktW = 64; KrealW = HH;
    }
    int shW = (nktW == 4) ? 2 : 6;
    // pre-split W_l into frag buffer, run xz GEMM
    split_matrix<<<dim3(512 * nktW / 4), 256, 0, stream>>>(
        Ws[layer], frag, KrealW, nktW, shW);
    gemm_mfma<<<dim3(64, 4), 256, 0, stream>>>(
        af, lo_off, t_stride, nktW, frag, bs[layer], xz);
    // pre-split U_l (overwrites W frags; stream-ordered after gemm)
    split_matrix<<<dim3(512 * 64 / 4), 256, 0, stream>>>(
        Us[layer], frag, HH, 64, 6);

    (void)hipMemsetAsync(allhf[layer], 0, 65536 * 2, stream);   // h frag slot 0
    (void)hipMemsetAsync(hT0, 0, 2 * HH * BB * 4, stream);      // hT0 + c
    for (int t = 0; t < TT; t++) {
      lstm_step<<<dim3(512), 256, 0, stream>>>(
          frag, xz + (size_t)t * BB * G4,
          allhf[layer] + (size_t)t * 65536, allhf[layer] + (size_t)(t + 1) * 65536,
          hping[t & 1], hping[(t + 1) & 1], cbuf, tokens, t);
    }
  }

  // final h (t=31) is in hT0
  smallgemm<<<dim3(HH / 32), 256, 0, stream>>>(hT0, Wd1, bd1, yT, HH, HH, 16, 1);
  smallgemm<<<dim3((VV + 31) / 32), 256, 0, stream>>>(yT, Wd2, bd2, logits, HH, VV, 1, VV);
  softmax_rows<<<dim3(BB), 256, 0, stream>>>(logits, out, VV);
}

// Round 5
// 1652.543 us; speedup vs baseline: 5.2943x; 1.1158x over previous
//
#include <hip/hip_runtime.h>
#include <hip/hip_bf16.h>
#include <cstddef>

#define BB 16
#define TT 32
#define VV 1003
#define EE 100
#define HH 2048
#define G4 8192  // 4*H

typedef __attribute__((ext_vector_type(8))) short s16x8;
typedef __attribute__((ext_vector_type(4))) float f32x4;

__device__ __forceinline__ unsigned short f2bf(float f) {
  unsigned u = __float_as_uint(f);
  u += 0x7fffu + ((u >> 16) & 1u);
  return (unsigned short)(u >> 16);
}
__device__ __forceinline__ float bf2f(unsigned short s) {
  return __uint_as_float(((unsigned)s) << 16);
}

// ---------------- embedding gather -> A-fragments (hi/lo bf16) ---------------
__global__ __launch_bounds__(256) void embed_frag(
    const int* __restrict__ tokens, const float* __restrict__ emb,
    short* __restrict__ xf) {
  int i = blockIdx.x * 256 + threadIdx.x;   // 32t * 16b * 128e
  if (i >= TT * BB * 128) return;
  int e = i & 127, b = (i >> 7) & 15, t = i >> 11;
  float v = 0.f;
  if (e < EE) v = emb[(size_t)tokens[b * TT + t] * EE + e];
  unsigned short hi = f2bf(v);
  unsigned short lo = f2bf(v - bf2f(hi));
  int kt = e >> 5, kk = e & 31;
  int lane = (kk >> 3) * 16 + b, j = kk & 7;
  size_t idx = (size_t)t * 4096 + ((size_t)kt * 64 + lane) * 8 + j;
  xf[idx] = (short)hi;
  xf[idx + 2048] = (short)lo;
}

// ---------------- pre-split fp32 matrix -> permuted B-fragments --------------
__global__ __launch_bounds__(256) void split_matrix(
    const float* __restrict__ src, short* __restrict__ dst,
    int Kreal, int nkt, int sh) {
  int tid = threadIdx.x, w = tid >> 6, L = tid & 63;
  int tile = blockIdx.x * 4 + w;
  int ct = tile >> sh, kt = tile & (nkt - 1);
  int cl = L & 15;
  int gcol = (cl >> 2) * HH + ct * 4 + (cl & 3);
  int r0 = kt * 32 + (L >> 4) * 8;
  s16x8 hh, ll;
#pragma unroll
  for (int j = 0; j < 8; j++) {
    int r = r0 + j;
    float v = (r < Kreal) ? src[(size_t)r * G4 + gcol] : 0.f;
    unsigned short h = f2bf(v);
    hh[j] = (short)h;
    ll[j] = (short)f2bf(v - bf2f(h));
  }
  size_t base = ((size_t)tile) * 1024 + L * 8;
  *(s16x8*)&dst[base] = hh;
  *(s16x8*)&dst[base + 512] = ll;
}

// ---------------- MFMA GEMM: xz (permuted cols) = A @ W + bias --------------
__global__ __launch_bounds__(256) void gemm_mfma(
    const short* __restrict__ af, int lo_off, int t_stride, int nkt,
    const short* __restrict__ wfrag, const float* __restrict__ bias,
    float* __restrict__ xz) {
  __shared__ __align__(16) short Bs[8][1024];
  int tid = threadIdx.x;
  int w = tid >> 6, L = tid & 63;
  int ct0 = blockIdx.x * 8;
  int t_a = blockIdx.y * 8 + w * 2;

  f32x4 acc0[8], acc1[8];
#pragma unroll
  for (int nt = 0; nt < 8; nt++) {
    acc0[nt] = (f32x4){0.f, 0.f, 0.f, 0.f};
    acc1[nt] = (f32x4){0.f, 0.f, 0.f, 0.f};
  }
  const short* Ah = af + (size_t)t_a * t_stride + L * 8;

  for (int kt = 0; kt < nkt; kt++) {
    s16x8 tmp[4];
#pragma unroll
    for (int q = 0; q < 4; q++) {
      int chunk = q * 256 + tid;
      int nt = chunk >> 7, idx = chunk & 127;
      tmp[q] = *(const s16x8*)&wfrag[((size_t)(ct0 + nt) * nkt + kt) * 1024 + idx * 8];
    }
    __syncthreads();
#pragma unroll
    for (int q = 0; q < 4; q++) {
      int chunk = q * 256 + tid;
      int nt = chunk >> 7, idx = chunk & 127;
      *(s16x8*)&Bs[nt][idx * 8] = tmp[q];
    }
    __syncthreads();

    s16x8 aH0 = *(const s16x8*)(Ah + kt * 512);
    s16x8 aL0 = *(const s16x8*)(Ah + lo_off + kt * 512);
    s16x8 aH1 = *(const s16x8*)(Ah + t_stride + kt * 512);
    s16x8 aL1 = *(const s16x8*)(Ah + t_stride + lo_off + kt * 512);
#pragma unroll
    for (int nt = 0; nt < 8; nt++) {
      s16x8 bH = *(const s16x8*)&Bs[nt][L * 8];
      s16x8 bL = *(const s16x8*)&Bs[nt][512 + L * 8];
      acc0[nt] = __builtin_amdgcn_mfma_f32_16x16x32_bf16(aH0, bH, acc0[nt], 0, 0, 0);
      acc0[nt] = __builtin_amdgcn_mfma_f32_16x16x32_bf16(aL0, bH, acc0[nt], 0, 0, 0);
      acc0[nt] = __builtin_amdgcn_mfma_f32_16x16x32_bf16(aH0, bL, acc0[nt], 0, 0, 0);
      acc1[nt] = __builtin_amdgcn_mfma_f32_16x16x32_bf16(aH1, bH, acc1[nt], 0, 0, 0);
      acc1[nt] = __builtin_amdgcn_mfma_f32_16x16x32_bf16(aL1, bH, acc1[nt], 0, 0, 0);
      acc1[nt] = __builtin_amdgcn_mfma_f32_16x16x32_bf16(aH1, bL, acc1[nt], 0, 0, 0);
    }
  }

  int nq = L >> 4, hl = L & 15;
#pragma unroll
  for (int nt = 0; nt < 8; nt++) {
    int ctg = ct0 + nt;
    int gcol = (hl >> 2) * HH + ctg * 4 + (hl & 3);
    float bv = bias[gcol];
#pragma unroll
    for (int r = 0; r < 4; r++) {
      int b = nq * 4 + r;
      xz[((size_t)t_a * 16 + b) * G4 + ctg * 16 + hl] = acc0[nt][r] + bv;
      xz[((size_t)(t_a + 1) * 16 + b) * G4 + ctg * 16 + hl] = acc1[nt][r] + bv;
    }
  }
}

// ---------------- one LSTM step, fused, pre-split U frags, 8 waves -----------
// grid 512 (1 col-tile = 4 hu x 4 gates each), 512 thr = 8 waves (K-eighths).
__global__ __launch_bounds__(512) void lstm_step(
    const short* __restrict__ Ufrag,   // pre-split, permuted tiles
    const float* __restrict__ xzt,     // [16][8192] permuted cols
    const short* __restrict__ hf_in,   // slot t  (A-frags)
    short* __restrict__ hf_out,        // slot t+1
    const float* __restrict__ hT_in,   // [2048][16] fp32
    float* __restrict__ hT_out,
    float* __restrict__ c,             // [16][2048]
    const int* __restrict__ tokens, int t) {
  __shared__ float red[8][16][16];
  __shared__ float zs[16][16];
  int tid = threadIdx.x, w = tid >> 6, L = tid & 63;
  int ct = blockIdx.x;

  f32x4 acc = {0.f, 0.f, 0.f, 0.f};
  const short* Ub = Ufrag + ((size_t)ct * 64 + w * 8) * 1024 + L * 8;
  const short* Hb = hf_in + (w * 8) * 512 + L * 8;

#pragma unroll
  for (int i = 0; i < 8; i++) {
    s16x8 bh = *(const s16x8*)(Ub + i * 1024);
    s16x8 bl = *(const s16x8*)(Ub + i * 1024 + 512);
    s16x8 ah = *(const s16x8*)(Hb + i * 512);
    s16x8 al = *(const s16x8*)(Hb + i * 512 + 32768);
    acc = __builtin_amdgcn_mfma_f32_16x16x32_bf16(ah, bh, acc, 0, 0, 0);
    acc = __builtin_amdgcn_mfma_f32_16x16x32_bf16(al, bh, acc, 0, 0, 0);
    acc = __builtin_amdgcn_mfma_f32_16x16x32_bf16(ah, bl, acc, 0, 0, 0);
  }
#pragma unroll
  for (int r = 0; r < 4; r++) red[w][(L >> 4) * 4 + r][L & 15] = acc[r];
  __syncthreads();

  if (tid < 256) {
    int b = tid >> 4, cl = tid & 15;
    float s = 0.f;
#pragma unroll
    for (int q = 0; q < 8; q++) s += red[q][b][cl];
    zs[b][cl] = s + xzt[(size_t)b * G4 + ct * 16 + cl];
  }
  __syncthreads();

  if (tid < 64) {
    int b = tid >> 2, hq = tid & 3;
    int hu = ct * 4 + hq;
    float z0 = zs[b][0 * 4 + hq];
    float z1 = zs[b][1 * 4 + hq];
    float z2 = zs[b][2 * 4 + hq];
    float z3 = zs[b][3 * 4 + hq];
    float ig = 1.f / (1.f + expf(-z0));
    float fg = 1.f / (1.f + expf(-z1));
    float gt = tanhf(z2);
    float og = 1.f / (1.f + expf(-z3));
    float c_old = c[(size_t)b * HH + hu];
    float cn = fg * c_old + ig * gt;
    float hn = og * tanhf(cn);
    if (tokens[b * TT + t] == 0) {
      cn = c_old;
      hn = hT_in[(size_t)hu * BB + b];
    }
    c[(size_t)b * HH + hu] = cn;
    hT_out[(size_t)hu * BB + b] = hn;
    unsigned short hi = f2bf(hn);
    unsigned short lo = f2bf(hn - bf2f(hi));
    int kt2 = hu >> 5, kk = hu & 31;
    int lane2 = (kk >> 3) * 16 + b, jj = kk & 7;
    size_t idx = ((size_t)kt2 * 64 + lane2) * 8 + jj;
    hf_out[idx] = (short)hi;
    hf_out[idx + 32768] = (short)lo;
  }
}

// ---------------- head stage 1: K-split partial GEMM -------------------------
// XT [K][16] k-major. grid (ceil(N/64), 8); block 256 = 4 kg x 64 lanes.
// chunk = by*4+kg owns k in [chunk*64 + ... ) wait: block ky-range 256, kg 64.
__global__ __launch_bounds__(256) void head_partial(
    const float* __restrict__ XT, const float* __restrict__ W,
    float* __restrict__ partial, int N) {
  __shared__ float xs[4096];  // 256 k x 16 b
  int tid = threadIdx.x;
  int k0 = blockIdx.y * 256;
  const float* src = XT + (size_t)k0 * 16;
  for (int i = tid; i < 4096; i += 256) xs[i] = src[i];
  __syncthreads();
  int kg = tid >> 6, lane = tid & 63;
  int col = blockIdx.x * 64 + lane;
  if (col >= N) return;
  float acc[16];
#pragma unroll
  for (int b = 0; b < 16; b++) acc[b] = 0.f;
  const float* Wp = W + (size_t)(k0 + kg * 64) * N + col;
  const float* xp = xs + kg * 64 * 16;
  for (int kk = 0; kk < 64; kk++) {
    float wv = Wp[(size_t)kk * N];
#pragma unroll
    for (int b = 0; b < 16; b++) acc[b] = fmaf(xp[kk * 16 + b], wv, acc[b]);
  }
  int chunk = blockIdx.y * 4 + kg;
#pragma unroll
  for (int b = 0; b < 16; b++)
    partial[((size_t)chunk * 16 + b) * N + col] = acc[b];
}

// ---------------- head stage 2: reduce 32 chunks + bias ----------------------
__global__ __launch_bounds__(256) void head_reduce(
    const float* __restrict__ partial, const float* __restrict__ bias,
    float* __restrict__ out, int N, int sc, int sb) {
  int i = blockIdx.x * 256 + threadIdx.x;
  if (i >= 16 * N) return;
  int b = i / N, col = i - b * N;
  float s = bias[col];
#pragma unroll 8
  for (int ch = 0; ch < 32; ch++) s += partial[((size_t)ch * 16 + b) * N + col];
  out[(size_t)col * sc + (size_t)b * sb] = s;
}

// ---------------- softmax over rows of [16][1003] ----------------
__global__ __launch_bounds__(256) void softmax_rows(
    const float* __restrict__ logits, float* __restrict__ out, int N) {
  __shared__ float buf[1024];
  __shared__ float wred[4];
  __shared__ float rmax, rsum;
  int b = blockIdx.x, tid = threadIdx.x;
  float m = -1e30f;
  for (int v = tid; v < N; v += 256) {
    float x = logits[(size_t)b * N + v];
    buf[v] = x;
    m = fmaxf(m, x);
  }
  for (int o = 32; o > 0; o >>= 1) m = fmaxf(m, __shfl_down(m, o, 64));
  if ((tid & 63) == 0) wred[tid >> 6] = m;
  __syncthreads();
  if (tid == 0) rmax = fmaxf(fmaxf(wred[0], wred[1]), fmaxf(wred[2], wred[3]));
  __syncthreads();
  float s = 0.f;
  for (int v = tid; v < N; v += 256) {
    float e = expf(buf[v] - rmax);
    buf[v] = e;
    s += e;
  }
  for (int o = 32; o > 0; o >>= 1) s += __shfl_down(s, o, 64);
  if ((tid & 63) == 0) wred[tid >> 6] = s;
  __syncthreads();
  if (tid == 0) rsum = wred[0] + wred[1] + wred[2] + wred[3];
  __syncthreads();
  float inv = 1.f / rsum;
  for (int v = tid; v < N; v += 256) out[(size_t)b * N + v] = buf[v] * inv;
}

extern "C" void kernel_launch(void* const* d_in, const int* in_sizes, int n_in,
                              void* d_out, int out_size, void* d_ws, size_t ws_size,
                              hipStream_t stream) {
  const int*   tokens = (const int*)d_in[0];
  const float* emb  = (const float*)d_in[1];
  const float* W1   = (const float*)d_in[2];
  const float* U1   = (const float*)d_in[3];
  const float* b1   = (const float*)d_in[4];
  const float* W2   = (const float*)d_in[5];
  const float* U2   = (const float*)d_in[6];
  const float* b2   = (const float*)d_in[7];
  const float* W3   = (const float*)d_in[8];
  const float* U3   = (const float*)d_in[9];
  const float* b3   = (const float*)d_in[10];
  const float* Wd1  = (const float*)d_in[11];
  const float* bd1  = (const float*)d_in[12];
  const float* Wd2  = (const float*)d_in[13];
  const float* bd2  = (const float*)d_in[14];
  float* out = (float*)d_out;

  char* base = (char*)d_ws;
  size_t off = 0;
  auto carve = [&](size_t bytes) -> char* {
    char* p = base + off;
    off += (bytes + 255) & ~(size_t)255;
    return p;
  };
  float* xz      = (float*)carve((size_t)TT * BB * G4 * 4);     // 16 MB
  short* allhf0  = (short*)carve(33ull * 65536 * 2);            // 4.33 MB
  short* allhf1  = (short*)carve(33ull * 65536 * 2);
  short* allhf2  = (short*)carve(33ull * 65536 * 2);
  short* xfrag   = (short*)carve((size_t)TT * 4096 * 2);        // 256 KB
  short* frag    = (short*)carve(512ull * 64 * 1024 * 2);       // 64 MB shared W/U frags
  float* hT0     = (float*)carve(2 * HH * BB * 4);              // hT0 + c contiguous
  float* cbuf    = hT0 + HH * BB;
  float* hT1     = (float*)carve(HH * BB * 4);
  float* yT      = (float*)carve(HH * BB * 4);
  float* logits  = (float*)carve(BB * 1024 * 4);
  float* partial = (float*)carve(32ull * 16 * HH * 4);          // 4 MB head partials

  short* allhf[3] = {allhf0, allhf1, allhf2};
  const float* Us[3] = {U1, U2, U3};
  const float* Ws[3] = {W1, W2, W3};
  const float* bs[3] = {b1, b2, b3};
  float* hping[2] = {hT0, hT1};

  embed_frag<<<dim3(256), 256, 0, stream>>>(tokens, emb, xfrag);

  for (int layer = 0; layer < 3; layer++) {
    const short* af;
    int lo_off, t_stride, nktW, KrealW;
    if (layer == 0) {
      af = xfrag; lo_off = 2048; t_stride = 4096; nktW = 4; KrealW = EE;
    } else {
      af = allhf[layer - 1] + 65536;  // slot 1 == h at t=0
      lo_off = 32768; t_stride = 65536; nktW = 64; KrealW = HH;
    }
    int shW = (nktW == 4) ? 2 : 6;
    split_matrix<<<dim3(512 * nktW / 4), 256, 0, stream>>>(
        Ws[layer], frag, KrealW, nktW, shW);
    gemm_mfma<<<dim3(64, 4), 256, 0, stream>>>(
        af, lo_off, t_stride, nktW, frag, bs[layer], xz);
    split_matrix<<<dim3(512 * 64 / 4), 256, 0, stream>>>(
        Us[layer], frag, HH, 64, 6);

    (void)hipMemsetAsync(allhf[layer], 0, 65536 * 2, stream);   // h frag slot 0
    (void)hipMemsetAsync(hT0, 0, 2 * HH * BB * 4, stream);      // hT0 + c
    for (int t = 0; t < TT; t++) {
      lstm_step<<<dim3(512), 512, 0, stream>>>(
          frag, xz + (size_t)t * BB * G4,
          allhf[layer] + (size_t)t * 65536, allhf[layer] + (size_t)(t + 1) * 65536,
          hping[t & 1], hping[(t + 1) & 1], cbuf, tokens, t);
    }
  }

  // final h (t=31) is in hT0
  head_partial<<<dim3(HH / 64, 8), 256, 0, stream>>>(hT0, Wd1, partial, HH);
  head_reduce<<<dim3((16 * HH + 255) / 256), 256, 0, stream>>>(partial, bd1, yT, HH, 16, 1);
  head_partial<<<dim3((VV + 63) / 64, 8), 256, 0, stream>>>(yT, Wd2, partial, VV);
  head_reduce<<<dim3((16 * VV + 255) / 256), 256, 0, stream>>>(partial, bd2, logits, VV, 1, VV);
  softmax_rows<<<dim3(BB), 256, 0, stream>>>(logits, out, VV);
}

// Round 6
// 1147.230 us; speedup vs baseline: 7.6262x; 1.4405x over previous
//
#include <hip/hip_runtime.h>
#include <hip/hip_bf16.h>
#include <cstddef>

#define BB 16
#define TT 32
#define VV 1003
#define EE 100
#define HH 2048
#define G4 8192  // 4*H

typedef __attribute__((ext_vector_type(8))) short s16x8;
typedef __attribute__((ext_vector_type(4))) float f32x4;

__device__ __forceinline__ unsigned short f2bf(float f) {
  unsigned u = __float_as_uint(f);
  u += 0x7fffu + ((u >> 16) & 1u);
  return (unsigned short)(u >> 16);
}
__device__ __forceinline__ float bf2f(unsigned short s) {
  return __uint_as_float(((unsigned)s) << 16);
}

// ---------------- embedding gather -> A-fragments (hi/lo bf16) ---------------
__global__ __launch_bounds__(256) void embed_frag(
    const int* __restrict__ tokens, const float* __restrict__ emb,
    short* __restrict__ xf) {
  int i = blockIdx.x * 256 + threadIdx.x;   // 32t * 16b * 128e
  if (i >= TT * BB * 128) return;
  int e = i & 127, b = (i >> 7) & 15, t = i >> 11;
  float v = 0.f;
  if (e < EE) v = emb[(size_t)tokens[b * TT + t] * EE + e];
  unsigned short hi = f2bf(v);
  unsigned short lo = f2bf(v - bf2f(hi));
  int kt = e >> 5, kk = e & 31;
  int lane = (kk >> 3) * 16 + b, j = kk & 7;
  size_t idx = (size_t)t * 4096 + ((size_t)kt * 64 + lane) * 8 + j;
  xf[idx] = (short)hi;
  xf[idx + 2048] = (short)lo;
}

// ---------------- pre-split fp32 matrix -> permuted B-fragments (hi+lo) ------
__global__ __launch_bounds__(256) void split_matrix(
    const float* __restrict__ src, short* __restrict__ dst,
    int Kreal, int nkt, int sh) {
  int tid = threadIdx.x, w = tid >> 6, L = tid & 63;
  int tile = blockIdx.x * 4 + w;
  int ct = tile >> sh, kt = tile & (nkt - 1);
  int cl = L & 15;
  int gcol = (cl >> 2) * HH + ct * 4 + (cl & 3);
  int r0 = kt * 32 + (L >> 4) * 8;
  s16x8 hh, ll;
#pragma unroll
  for (int j = 0; j < 8; j++) {
    int r = r0 + j;
    float v = (r < Kreal) ? src[(size_t)r * G4 + gcol] : 0.f;
    unsigned short h = f2bf(v);
    hh[j] = (short)h;
    ll[j] = (short)f2bf(v - bf2f(h));
  }
  size_t base = ((size_t)tile) * 1024 + L * 8;
  *(s16x8*)&dst[base] = hh;
  *(s16x8*)&dst[base + 512] = ll;
}

// ---------------- pre-split U -> compact hi-only B-fragments -----------------
// tile = ct*64 + kt; dst stride 512 shorts per tile.
__global__ __launch_bounds__(256) void split_matrix_hi(
    const float* __restrict__ src, short* __restrict__ dst) {
  int tid = threadIdx.x, w = tid >> 6, L = tid & 63;
  int tile = blockIdx.x * 4 + w;
  int ct = tile >> 6, kt = tile & 63;
  int cl = L & 15;
  int gcol = (cl >> 2) * HH + ct * 4 + (cl & 3);
  int r0 = kt * 32 + (L >> 4) * 8;
  s16x8 hh;
#pragma unroll
  for (int j = 0; j < 8; j++) {
    float v = src[(size_t)(r0 + j) * G4 + gcol];
    hh[j] = (short)f2bf(v);
  }
  *(s16x8*)&dst[(size_t)tile * 512 + L * 8] = hh;
}

// ---------------- MFMA GEMM: xz (permuted cols) = A @ W + bias --------------
__global__ __launch_bounds__(256) void gemm_mfma(
    const short* __restrict__ af, int lo_off, int t_stride, int nkt,
    const short* __restrict__ wfrag, const float* __restrict__ bias,
    float* __restrict__ xz) {
  __shared__ __align__(16) short Bs[8][1024];
  int tid = threadIdx.x;
  int w = tid >> 6, L = tid & 63;
  int ct0 = blockIdx.x * 8;
  int t_a = blockIdx.y * 8 + w * 2;

  f32x4 acc0[8], acc1[8];
#pragma unroll
  for (int nt = 0; nt < 8; nt++) {
    acc0[nt] = (f32x4){0.f, 0.f, 0.f, 0.f};
    acc1[nt] = (f32x4){0.f, 0.f, 0.f, 0.f};
  }
  const short* Ah = af + (size_t)t_a * t_stride + L * 8;

  for (int kt = 0; kt < nkt; kt++) {
    s16x8 tmp[4];
#pragma unroll
    for (int q = 0; q < 4; q++) {
      int chunk = q * 256 + tid;
      int nt = chunk >> 7, idx = chunk & 127;
      tmp[q] = *(const s16x8*)&wfrag[((size_t)(ct0 + nt) * nkt + kt) * 1024 + idx * 8];
    }
    __syncthreads();
#pragma unroll
    for (int q = 0; q < 4; q++) {
      int chunk = q * 256 + tid;
      int nt = chunk >> 7, idx = chunk & 127;
      *(s16x8*)&Bs[nt][idx * 8] = tmp[q];
    }
    __syncthreads();

    s16x8 aH0 = *(const s16x8*)(Ah + kt * 512);
    s16x8 aL0 = *(const s16x8*)(Ah + lo_off + kt * 512);
    s16x8 aH1 = *(const s16x8*)(Ah + t_stride + kt * 512);
    s16x8 aL1 = *(const s16x8*)(Ah + t_stride + lo_off + kt * 512);
#pragma unroll
    for (int nt = 0; nt < 8; nt++) {
      s16x8 bH = *(const s16x8*)&Bs[nt][L * 8];
      s16x8 bL = *(const s16x8*)&Bs[nt][512 + L * 8];
      acc0[nt] = __builtin_amdgcn_mfma_f32_16x16x32_bf16(aH0, bH, acc0[nt], 0, 0, 0);
      acc0[nt] = __builtin_amdgcn_mfma_f32_16x16x32_bf16(aL0, bH, acc0[nt], 0, 0, 0);
      acc0[nt] = __builtin_amdgcn_mfma_f32_16x16x32_bf16(aH0, bL, acc0[nt], 0, 0, 0);
      acc1[nt] = __builtin_amdgcn_mfma_f32_16x16x32_bf16(aH1, bH, acc1[nt], 0, 0, 0);
      acc1[nt] = __builtin_amdgcn_mfma_f32_16x16x32_bf16(aL1, bH, acc1[nt], 0, 0, 0);
      acc1[nt] = __builtin_amdgcn_mfma_f32_16x16x32_bf16(aH1, bL, acc1[nt], 0, 0, 0);
    }
  }

  int nq = L >> 4, hl = L & 15;
#pragma unroll
  for (int nt = 0; nt < 8; nt++) {
    int ctg = ct0 + nt;
    int gcol = (hl >> 2) * HH + ctg * 4 + (hl & 3);
    float bv = bias[gcol];
#pragma unroll
    for (int r = 0; r < 4; r++) {
      int b = nq * 4 + r;
      xz[((size_t)t_a * 16 + b) * G4 + ctg * 16 + hl] = acc0[nt][r] + bv;
      xz[((size_t)(t_a + 1) * 16 + b) * G4 + ctg * 16 + hl] = acc1[nt][r] + bv;
    }
  }
}

// ---------------- one LSTM step, fused, hi-only U frags, 16 waves ------------
// grid 512 (1 col-tile = 4 hu x 4 gates each), 1024 thr = 16 waves (K/16 each).
// z = h_hi @ U_hi + h_lo @ U_hi  (U lo-part dropped; h precision kept).
__global__ __launch_bounds__(1024, 8) void lstm_step(
    const short* __restrict__ Ufrag,   // compact hi-only tiles [ct*64+f][512]
    const float* __restrict__ xzt,     // [16][8192] permuted cols
    const short* __restrict__ hf_in,   // slot t  (A-frags hi/lo)
    short* __restrict__ hf_out,        // slot t+1
    const float* __restrict__ hT_in,   // [2048][16] fp32
    float* __restrict__ hT_out,
    float* __restrict__ c,             // [16][2048]
    const int* __restrict__ tokens, int t) {
  __shared__ float red[16][16][16];
  __shared__ float zs[16][16];
  int tid = threadIdx.x, w = tid >> 6, L = tid & 63;
  int ct = blockIdx.x;

  f32x4 acc = {0.f, 0.f, 0.f, 0.f};
  const short* Ub = Ufrag + ((size_t)ct * 64 + w * 4) * 512 + L * 8;
  const short* Hb = hf_in + (w * 4) * 512 + L * 8;

#pragma unroll
  for (int i = 0; i < 4; i++) {
    s16x8 bh = *(const s16x8*)(Ub + i * 512);
    s16x8 ah = *(const s16x8*)(Hb + i * 512);
    s16x8 al = *(const s16x8*)(Hb + i * 512 + 32768);
    acc = __builtin_amdgcn_mfma_f32_16x16x32_bf16(ah, bh, acc, 0, 0, 0);
    acc = __builtin_amdgcn_mfma_f32_16x16x32_bf16(al, bh, acc, 0, 0, 0);
  }
#pragma unroll
  for (int r = 0; r < 4; r++) red[w][(L >> 4) * 4 + r][L & 15] = acc[r];
  __syncthreads();

  if (tid < 256) {
    int b = tid >> 4, cl = tid & 15;
    float s = 0.f;
#pragma unroll
    for (int q = 0; q < 16; q++) s += red[q][b][cl];
    zs[b][cl] = s + xzt[(size_t)b * G4 + ct * 16 + cl];
  }
  __syncthreads();

  if (tid < 64) {
    int b = tid >> 2, hq = tid & 3;
    int hu = ct * 4 + hq;
    float z0 = zs[b][0 * 4 + hq];
    float z1 = zs[b][1 * 4 + hq];
    float z2 = zs[b][2 * 4 + hq];
    float z3 = zs[b][3 * 4 + hq];
    float ig = 1.f / (1.f + expf(-z0));
    float fg = 1.f / (1.f + expf(-z1));
    float gt = tanhf(z2);
    float og = 1.f / (1.f + expf(-z3));
    float c_old = c[(size_t)b * HH + hu];
    float cn = fg * c_old + ig * gt;
    float hn = og * tanhf(cn);
    if (tokens[b * TT + t] == 0) {
      cn = c_old;
      hn = hT_in[(size_t)hu * BB + b];
    }
    c[(size_t)b * HH + hu] = cn;
    hT_out[(size_t)hu * BB + b] = hn;
    unsigned short hi = f2bf(hn);
    unsigned short lo = f2bf(hn - bf2f(hi));
    int kt2 = hu >> 5, kk = hu & 31;
    int lane2 = (kk >> 3) * 16 + b, jj = kk & 7;
    size_t idx = ((size_t)kt2 * 64 + lane2) * 8 + jj;
    hf_out[idx] = (short)hi;
    hf_out[idx + 32768] = (short)lo;
  }
}

// ---------------- head stage 1: K-split partial GEMM -------------------------
__global__ __launch_bounds__(256) void head_partial(
    const float* __restrict__ XT, const float* __restrict__ W,
    float* __restrict__ partial, int N) {
  __shared__ float xs[4096];  // 256 k x 16 b
  int tid = threadIdx.x;
  int k0 = blockIdx.y * 256;
  const float* src = XT + (size_t)k0 * 16;
  for (int i = tid; i < 4096; i += 256) xs[i] = src[i];
  __syncthreads();
  int kg = tid >> 6, lane = tid & 63;
  int col = blockIdx.x * 64 + lane;
  if (col >= N) return;
  float acc[16];
#pragma unroll
  for (int b = 0; b < 16; b++) acc[b] = 0.f;
  const float* Wp = W + (size_t)(k0 + kg * 64) * N + col;
  const float* xp = xs + kg * 64 * 16;
  for (int kk = 0; kk < 64; kk++) {
    float wv = Wp[(size_t)kk * N];
#pragma unroll
    for (int b = 0; b < 16; b++) acc[b] = fmaf(xp[kk * 16 + b], wv, acc[b]);
  }
  int chunk = blockIdx.y * 4 + kg;
#pragma unroll
  for (int b = 0; b < 16; b++)
    partial[((size_t)chunk * 16 + b) * N + col] = acc[b];
}

// ---------------- head stage 2: reduce 32 chunks + bias ----------------------
__global__ __launch_bounds__(256) void head_reduce(
    const float* __restrict__ partial, const float* __restrict__ bias,
    float* __restrict__ out, int N, int sc, int sb) {
  int i = blockIdx.x * 256 + threadIdx.x;
  if (i >= 16 * N) return;
  int b = i / N, col = i - b * N;
  float s = bias[col];
#pragma unroll 8
  for (int ch = 0; ch < 32; ch++) s += partial[((size_t)ch * 16 + b) * N + col];
  out[(size_t)col * sc + (size_t)b * sb] = s;
}

// ---------------- softmax over rows of [16][1003] ----------------
__global__ __launch_bounds__(256) void softmax_rows(
    const float* __restrict__ logits, float* __restrict__ out, int N) {
  __shared__ float buf[1024];
  __shared__ float wred[4];
  __shared__ float rmax, rsum;
  int b = blockIdx.x, tid = threadIdx.x;
  float m = -1e30f;
  for (int v = tid; v < N; v += 256) {
    float x = logits[(size_t)b * N + v];
    buf[v] = x;
    m = fmaxf(m, x);
  }
  for (int o = 32; o > 0; o >>= 1) m = fmaxf(m, __shfl_down(m, o, 64));
  if ((tid & 63) == 0) wred[tid >> 6] = m;
  __syncthreads();
  if (tid == 0) rmax = fmaxf(fmaxf(wred[0], wred[1]), fmaxf(wred[2], wred[3]));
  __syncthreads();
  float s = 0.f;
  for (int v = tid; v < N; v += 256) {
    float e = expf(buf[v] - rmax);
    buf[v] = e;
    s += e;
  }
  for (int o = 32; o > 0; o >>= 1) s += __shfl_down(s, o, 64);
  if ((tid & 63) == 0) wred[tid >> 6] = s;
  __syncthreads();
  if (tid == 0) rsum = wred[0] + wred[1] + wred[2] + wred[3];
  __syncthreads();
  float inv = 1.f / rsum;
  for (int v = tid; v < N; v += 256) out[(size_t)b * N + v] = buf[v] * inv;
}

extern "C" void kernel_launch(void* const* d_in, const int* in_sizes, int n_in,
                              void* d_out, int out_size, void* d_ws, size_t ws_size,
                              hipStream_t stream) {
  const int*   tokens = (const int*)d_in[0];
  const float* emb  = (const float*)d_in[1];
  const float* W1   = (const float*)d_in[2];
  const float* U1   = (const float*)d_in[3];
  const float* b1   = (const float*)d_in[4];
  const float* W2   = (const float*)d_in[5];
  const float* U2   = (const float*)d_in[6];
  const float* b2   = (const float*)d_in[7];
  const float* W3   = (const float*)d_in[8];
  const float* U3   = (const float*)d_in[9];
  const float* b3   = (const float*)d_in[10];
  const float* Wd1  = (const float*)d_in[11];
  const float* bd1  = (const float*)d_in[12];
  const float* Wd2  = (const float*)d_in[13];
  const float* bd2  = (const float*)d_in[14];
  float* out = (float*)d_out;

  char* base = (char*)d_ws;
  size_t off = 0;
  auto carve = [&](size_t bytes) -> char* {
    char* p = base + off;
    off += (bytes + 255) & ~(size_t)255;
    return p;
  };
  float* xz      = (float*)carve((size_t)TT * BB * G4 * 4);     // 16 MB
  short* allhf0  = (short*)carve(33ull * 65536 * 2);            // 4.33 MB
  short* allhf1  = (short*)carve(33ull * 65536 * 2);
  short* allhf2  = (short*)carve(33ull * 65536 * 2);
  short* xfrag   = (short*)carve((size_t)TT * 4096 * 2);        // 256 KB
  short* frag    = (short*)carve(512ull * 64 * 1024 * 2);       // 64 MB shared W/U frags
  float* hT0     = (float*)carve(2 * HH * BB * 4);              // hT0 + c contiguous
  float* cbuf    = hT0 + HH * BB;
  float* hT1     = (float*)carve(HH * BB * 4);
  float* yT      = (float*)carve(HH * BB * 4);
  float* logits  = (float*)carve(BB * 1024 * 4);
  float* partial = (float*)carve(32ull * 16 * HH * 4);          // 4 MB head partials

  short* allhf[3] = {allhf0, allhf1, allhf2};
  const float* Us[3] = {U1, U2, U3};
  const float* Ws[3] = {W1, W2, W3};
  const float* bs[3] = {b1, b2, b3};
  float* hping[2] = {hT0, hT1};

  embed_frag<<<dim3(256), 256, 0, stream>>>(tokens, emb, xfrag);

  for (int layer = 0; layer < 3; layer++) {
    const short* af;
    int lo_off, t_stride, nktW, KrealW;
    if (layer == 0) {
      af = xfrag; lo_off = 2048; t_stride = 4096; nktW = 4; KrealW = EE;
    } else {
      af = allhf[layer - 1] + 65536;  // slot 1 == h at t=0
      lo_off = 32768; t_stride = 65536; nktW = 64; KrealW = HH;
    }
    int shW = (nktW == 4) ? 2 : 6;
    split_matrix<<<dim3(512 * nktW / 4), 256, 0, stream>>>(
        Ws[layer], frag, KrealW, nktW, shW);
    gemm_mfma<<<dim3(64, 4), 256, 0, stream>>>(
        af, lo_off, t_stride, nktW, frag, bs[layer], xz);
    // compact hi-only U frags (overwrite W frags; stream-ordered after gemm)
    split_matrix_hi<<<dim3(512 * 64 / 4), 256, 0, stream>>>(Us[layer], frag);

    (void)hipMemsetAsync(allhf[layer], 0, 65536 * 2, stream);   // h frag slot 0
    (void)hipMemsetAsync(hT0, 0, 2 * HH * BB * 4, stream);      // hT0 + c
    for (int t = 0; t < TT; t++) {
      lstm_step<<<dim3(512), 1024, 0, stream>>>(
          frag, xz + (size_t)t * BB * G4,
          allhf[layer] + (size_t)t * 65536, allhf[layer] + (size_t)(t + 1) * 65536,
          hping[t & 1], hping[(t + 1) & 1], cbuf, tokens, t);
    }
  }

  // final h (t=31) is in hT0
  head_partial<<<dim3(HH / 64, 8), 256, 0, stream>>>(hT0, Wd1, partial, HH);
  head_reduce<<<dim3((16 * HH + 255) / 256), 256, 0, stream>>>(partial, bd1, yT, HH, 16, 1);
  head_partial<<<dim3((VV + 63) / 64, 8), 256, 0, stream>>>(yT, Wd2, partial, VV);
  head_reduce<<<dim3((16 * VV + 255) / 256), 256, 0, stream>>>(partial, bd2, logits, VV, 1, VV);
  softmax_rows<<<dim3(BB), 256, 0, stream>>>(logits, out, VV);
}